// Round 9
// baseline (996.266 us; speedup 1.0000x reference)
//
#include <hip/hip_runtime.h>
#include <math.h>

#define TBn 16
#define Lpx 3136
#define CHW 301056      // 96*3136
#define SZn 4816896     // 16*96*3136
#define PRJ 1605632     // 16*32*3136
#define NPAD 3328       // 256*13

__device__ __forceinline__ float siluf_(float z){ return z / (1.f + expf(-z)); }
__device__ __forceinline__ float softplusf_(float z){ return fmaxf(z,0.f) + log1pf(expf(-fabsf(z))); }

// ---------------- per-pixel channel matmul: out[n,co,p] = sum_ci W[co,ci]*in[n,ci,p] (+bias) ----------------
__global__ __launch_bounds__(256) void k_matmul(const float* __restrict__ in, const float* __restrict__ Wm,
                                                const float* __restrict__ bias, float* __restrict__ out){
  int blk = blockIdx.x;
  int n = blk / 49, pt = blk % 49, p0 = pt * 64;
  __shared__ float lx[96*64];    // [ci][px]
  __shared__ float wl[96*33];    // [co][ci(32)+pad]
  int tid = threadIdx.x;
  const float* inb = in + (size_t)n*CHW;
  for (int i = tid; i < 96*64; i += 256){
    int ci = i >> 6, px = i & 63;
    lx[i] = inb[(size_t)ci*Lpx + p0 + px];
  }
  int px_t = tid & 15, co_t = tid >> 4;   // px base px_t*4, co base co_t*6
  float acc[6][4];
  #pragma unroll
  for (int j = 0; j < 6; ++j){
    float b = bias ? bias[co_t*6 + j] : 0.f;
    #pragma unroll
    for (int q = 0; q < 4; ++q) acc[j][q] = b;
  }
  for (int cc = 0; cc < 3; ++cc){
    __syncthreads();
    for (int i = tid; i < 96*32; i += 256){
      int co = i >> 5, ci = i & 31;
      wl[co*33 + ci] = Wm[co*96 + cc*32 + ci];
    }
    __syncthreads();
    for (int ci = 0; ci < 32; ++ci){
      float4 xv = *(const float4*)&lx[(cc*32 + ci)*64 + px_t*4];
      #pragma unroll
      for (int j = 0; j < 6; ++j){
        float w = wl[(co_t*6 + j)*33 + ci];
        acc[j][0] = fmaf(w, xv.x, acc[j][0]);
        acc[j][1] = fmaf(w, xv.y, acc[j][1]);
        acc[j][2] = fmaf(w, xv.z, acc[j][2]);
        acc[j][3] = fmaf(w, xv.w, acc[j][3]);
      }
    }
  }
  float* ob = out + (size_t)n*CHW + p0 + px_t*4;
  #pragma unroll
  for (int j = 0; j < 6; ++j){
    float4 v; v.x = acc[j][0]; v.y = acc[j][1]; v.z = acc[j][2]; v.w = acc[j][3];
    *(float4*)&ob[(size_t)(co_t*6 + j)*Lpx] = v;
  }
}

// ---------------- LIF over 16 steps, float4, uchar spike output ----------------
__global__ __launch_bounds__(256) void k_lif1(const float* __restrict__ xp, unsigned char* __restrict__ sp){
  int i4 = blockIdx.x*256 + threadIdx.x;     // < CHW/4
  float4 v = {0.f,0.f,0.f,0.f};
  #pragma unroll
  for (int t = 0; t < 16; ++t){
    float4 z = *(const float4*)&xp[(size_t)t*CHW + (size_t)i4*4];
    v.x = 0.5f*(v.x + z.x); v.y = 0.5f*(v.y + z.y);
    v.z = 0.5f*(v.z + z.z); v.w = 0.5f*(v.w + z.w);
    uchar4 s;
    s.x = (v.x >= 1.0f); s.y = (v.y >= 1.0f); s.z = (v.z >= 1.0f); s.w = (v.w >= 1.0f);
    *(uchar4*)&sp[(size_t)t*CHW + (size_t)i4*4] = s;
    v.x = s.x ? 0.f : v.x; v.y = s.y ? 0.f : v.y;
    v.z = s.z ? 0.f : v.z; v.w = s.w ? 0.f : v.w;
  }
}

// ---------------- dense 3x3 conv (96->96) + bias + silu, v4 ----------------
// v3 + x-reads via 2x aligned ds_read_b128 per row into statically-indexed xr[3][8]
// (replaces 18 3-way-conflicting b32 reads per ci with 6 b128 reads).
#define CIC3 8
__global__ __launch_bounds__(256) void k_conv4(const unsigned char* __restrict__ spk, const float* __restrict__ cw,
                                               const float* __restrict__ cb, float* __restrict__ out){
  int b = blockIdx.x, cog = blockIdx.y, hb = blockIdx.z;
  int co0 = cog*16, h0 = hb*4;
  int tid = threadIdx.x;
  int hl = tid / 56, rem2 = tid % 56;
  int coh = rem2 / 14, wq = rem2 % 14;       // active if tid < 224
  bool act = tid < 224;
  __shared__ float xl[CIC3*6*60];            // [ci][row 0..5][col 0..57, stride 60]
  __shared__ float wl[CIC3*9*16];            // [ci][tap][co]
  float acc[4][4];
  #pragma unroll
  for (int j = 0; j < 4; ++j)
    #pragma unroll
    for (int q = 0; q < 4; ++q) acc[j][q] = 0.f;

  for (int cc = 0; cc < 12; ++cc){
    __syncthreads();
    for (int i = tid; i < CIC3*6*58; i += 256){
      int ci = i / 348, rem = i % 348;
      int hh = rem / 58, ww = rem % 58;
      int sh = h0 - 1 + hh, sw = ww - 1;
      float v = 0.f;
      if (sh >= 0 && sh < 56 && sw >= 0 && sw < 56)
        v = (float)spk[(((size_t)b*96 + cc*CIC3 + ci)*56 + sh)*56 + sw];
      xl[ci*360 + hh*60 + ww] = v;
    }
    for (int i = tid; i < CIC3*9*16; i += 256){
      int ci = i / 144, rem = i % 144;
      int tap = rem / 16, co = rem % 16;
      wl[i] = cw[(((size_t)(co0+co))*96 + cc*CIC3 + ci)*9 + tap];
    }
    __syncthreads();
    if (act){
      for (int ci = 0; ci < CIC3; ++ci){
        float xr[3][8];
        int base = ci*360 + hl*60 + wq*4;
        #pragma unroll
        for (int dh = 0; dh < 3; ++dh){
          float4 a = *(const float4*)&xl[base + dh*60];
          float4 c = *(const float4*)&xl[base + dh*60 + 4];
          xr[dh][0] = a.x; xr[dh][1] = a.y; xr[dh][2] = a.z; xr[dh][3] = a.w;
          xr[dh][4] = c.x; xr[dh][5] = c.y; xr[dh][6] = c.z; xr[dh][7] = c.w;
        }
        #pragma unroll
        for (int tap = 0; tap < 9; ++tap){
          const int dh = tap/3, dw = tap%3;
          float4 w = *(const float4*)&wl[(ci*9 + tap)*16 + coh*4];
          #pragma unroll
          for (int q = 0; q < 4; ++q){
            float xv = xr[dh][q + dw];
            acc[0][q] = fmaf(xv, w.x, acc[0][q]);
            acc[1][q] = fmaf(xv, w.y, acc[1][q]);
            acc[2][q] = fmaf(xv, w.z, acc[2][q]);
            acc[3][q] = fmaf(xv, w.w, acc[3][q]);
          }
        }
      }
    }
  }
  if (act){
    #pragma unroll
    for (int j = 0; j < 4; ++j){
      int co = co0 + coh*4 + j;
      float bv = cb[co];
      float4 o;
      o.x = siluf_(acc[j][0] + bv); o.y = siluf_(acc[j][1] + bv);
      o.z = siluf_(acc[j][2] + bv); o.w = siluf_(acc[j][3] + bv);
      *(float4*)&out[(((size_t)b*96 + co)*56 + h0 + hl)*56 + wq*4] = o;
    }
  }
}

// ---------------- depthwise 3x3 + silu, writes row-major and transposed ----------------
__global__ __launch_bounds__(256) void k_dwconv(const float* __restrict__ xin, const float* __restrict__ dwW,
                                                float* __restrict__ out, float* __restrict__ outT){
  int bd = blockIdx.x;           // b*96+d
  int d = bd % 96;
  const float* ip = xin + (size_t)bd*Lpx;
  __shared__ float pl[Lpx];
  __shared__ float po[Lpx + 56];
  int tid = threadIdx.x;
  for (int i = tid; i < Lpx; i += 256) pl[i] = ip[i];
  float w9[9];
  #pragma unroll
  for (int t = 0; t < 9; ++t) w9[t] = dwW[d*9 + t];
  __syncthreads();
  for (int i = tid; i < Lpx; i += 256){
    int h = i / 56, w = i % 56;
    float s = 0.f;
    #pragma unroll
    for (int tap = 0; tap < 9; ++tap){
      int hh = h + tap/3 - 1, ww = w + tap%3 - 1;
      if (hh >= 0 && hh < 56 && ww >= 0 && ww < 56) s = fmaf(pl[hh*56 + ww], w9[tap], s);
    }
    po[i + i/56] = siluf_(s);
  }
  __syncthreads();
  float* op  = out  + (size_t)bd*Lpx;
  float* otp = outT + (size_t)bd*Lpx;
  for (int i = tid; i < Lpx; i += 256){
    op[i] = po[i + i/56];
    int q = (i % 56)*56 + i/56;
    otp[i] = po[q + q/56];        // stride-57 LDS read: conflict-free
  }
}

// ---------------- per-pixel 96->(4k x 8r) projections, row-major and transposed ----------------
__global__ __launch_bounds__(256) void k_proj(const float* __restrict__ xss, const float* __restrict__ xpw,
                                              float* __restrict__ PROJ, float* __restrict__ PROJT){
  int b = blockIdx.x / 56, h = blockIdx.x % 56;
  __shared__ float lx[96*56];    // [d][w]
  __shared__ float lw[32*96];    // [kr][d]
  int tid = threadIdx.x;
  const float* xb = xss + (size_t)b*CHW + h*56;
  for (int i = tid; i < 96*56; i += 256){
    int d = i / 56, w = i % 56;
    lx[i] = xb[(size_t)d*Lpx + w];
  }
  for (int i = tid; i < 32*96; i += 256) lw[i] = xpw[i];
  __syncthreads();
  for (int o = tid; o < 32*56; o += 256){
    int w = o % 56, kr = o / 56;
    float s = 0.f;
    for (int d = 0; d < 96; ++d) s = fmaf(lx[d*56 + w], lw[kr*96 + d], s);
    size_t base = ((size_t)b*32 + kr)*Lpx;
    PROJ[base + h*56 + w] = s;
    PROJT[base + w*56 + h] = s;
  }
}

// ---------------- block-parallel bidirectional selective scan ----------------
__global__ __launch_bounds__(256) void k_scan2(const float* __restrict__ x_rm, const float* __restrict__ x_cm,
                                               const float* __restrict__ PROJ, const float* __restrict__ PROJT,
                                               const float* __restrict__ dtw_all, const float* __restrict__ dtb_all,
                                               const float* __restrict__ Alog, const float* __restrict__ Dall,
                                               float* __restrict__ out0, float* __restrict__ out1){
  int bd = blockIdx.x; int b = bd / 96, d = bd % 96;
  int klo = blockIdx.y;
  const float* xv = (klo == 0 ? x_rm : x_cm) + (size_t)bd*Lpx;
  const float* PR = (klo == 0 ? PROJ : PROJT);
  float* yo = (klo == 0 ? out0 : out1) + (size_t)bd*Lpx;
  int kA = klo, kB = klo + 2;

  float dwA[6], dwB[6];
  #pragma unroll
  for (int r = 0; r < 6; ++r){ dwA[r] = dtw_all[(kA*96 + d)*6 + r]; dwB[r] = dtw_all[(kB*96 + d)*6 + r]; }
  float biA = dtb_all[kA*96 + d], biB = dtb_all[kB*96 + d];
  float AA = -expf(Alog[kA*96 + d]), AB = -expf(Alog[kB*96 + d]);
  float Dsum = Dall[kA*96 + d] + Dall[kB*96 + d];
  const float* pA = PR + ((size_t)b*32 + kA*8)*Lpx;
  const float* pB = PR + ((size_t)b*32 + kB*8)*Lpx;

  __shared__ float xb[Lpx];
  __shared__ float u[NPAD];
  __shared__ float v[NPAD];
  __shared__ float yacc[Lpx + 56];
  __shared__ float wag[8];

  int tid = threadIdx.x;
  int lane = tid & 63, wv = tid >> 6;
  int base = tid * 13;

  for (int i = tid; i < Lpx; i += 256) xb[i] = xv[i];

  // ======== direction A (forward in p) ========
  for (int i = tid; i < Lpx; i += 256){
    float z = biA;
    #pragma unroll
    for (int r = 0; r < 6; ++r) z = fmaf(dwA[r], pA[(size_t)r*Lpx + i], z);
    float dt = softplusf_(z);
    u[i] = expf(dt * AA);
    v[i] = dt * pA[(size_t)6*Lpx + i] * xb[i];
  }
  for (int i = Lpx + tid; i < NPAD; i += 256){ u[i] = 1.f; v[i] = 0.f; }
  __syncthreads();

  {
    float a = 1.f, bb = 0.f;
    #pragma unroll
    for (int j = 0; j < 13; ++j){
      float da = u[base + j], db = v[base + j];
      bb = fmaf(da, bb, db);
      a *= da;
      u[base + j] = a; v[base + j] = bb;
    }
    float aT = a, bT = bb;
    #pragma unroll
    for (int off = 1; off < 64; off <<= 1){
      float ap = __shfl_up(aT, off), bp = __shfl_up(bT, off);
      if (lane >= off){ bT = fmaf(aT, bp, bT); aT *= ap; }
    }
    if (lane == 63){ wag[wv] = aT; wag[4 + wv] = bT; }
    float a_ex = __shfl_up(aT, 1), b_ex = __shfl_up(bT, 1);
    if (lane == 0){ a_ex = 1.f; b_ex = 0.f; }
    __syncthreads();
    float hw = 0.f;
    for (int j = 0; j < wv; ++j) hw = fmaf(wag[j], hw, wag[4 + j]);
    float hin = fmaf(a_ex, hw, b_ex);
    #pragma unroll
    for (int j = 0; j < 13; ++j)
      v[base + j] = fmaf(u[base + j], hin, v[base + j]);
  }
  __syncthreads();
  for (int i = tid; i < Lpx; i += 256){
    float C = pA[(size_t)7*Lpx + i];
    yacc[i + i/56] = fmaf(C, v[i], Dsum * xb[i]);
  }
  __syncthreads();

  // ======== direction B (reverse in p) ========
  for (int i = tid; i < Lpx; i += 256){
    float z = biB;
    #pragma unroll
    for (int r = 0; r < 6; ++r) z = fmaf(dwB[r], pB[(size_t)r*Lpx + i], z);
    float dt = softplusf_(z);
    u[i] = expf(dt * AB);
    v[i] = dt * pB[(size_t)6*Lpx + i] * xb[i];
  }
  for (int i = Lpx + tid; i < NPAD; i += 256){ u[i] = 1.f; v[i] = 0.f; }
  __syncthreads();

  {
    float a = 1.f, bb = 0.f;
    #pragma unroll
    for (int j = 12; j >= 0; --j){
      float da = u[base + j], db = v[base + j];
      bb = fmaf(da, bb, db);
      a *= da;
      u[base + j] = a; v[base + j] = bb;
    }
    float aT = a, bT = bb;
    #pragma unroll
    for (int off = 1; off < 64; off <<= 1){
      float ap = __shfl_down(aT, off), bp = __shfl_down(bT, off);
      if (lane + off < 64){ bT = fmaf(aT, bp, bT); aT *= ap; }
    }
    if (lane == 0){ wag[wv] = aT; wag[4 + wv] = bT; }
    float a_ex = __shfl_down(aT, 1), b_ex = __shfl_down(bT, 1);
    if (lane == 63){ a_ex = 1.f; b_ex = 0.f; }
    __syncthreads();
    float hw = 0.f;
    for (int j = 3; j > wv; --j) hw = fmaf(wag[j], hw, wag[4 + j]);
    float hin = fmaf(a_ex, hw, b_ex);
    #pragma unroll
    for (int j = 0; j < 13; ++j)
      v[base + j] = fmaf(u[base + j], hin, v[base + j]);
  }
  __syncthreads();
  for (int i = tid; i < Lpx; i += 256){
    float C = pB[(size_t)7*Lpx + i];
    yacc[i + i/56] = fmaf(C, v[i], yacc[i + i/56]);
  }
  __syncthreads();

  if (klo == 0){
    for (int i = tid; i < Lpx; i += 256)
      yo[i] = yacc[i + i/56];
  } else {
    for (int i = tid; i < Lpx; i += 256){
      int q = (i % 56)*56 + i/56;
      yo[i] = yacc[q + q/56];
    }
  }
}

// ---------------- combine ya+yb, LayerNorm over channels (float4) ----------------
__global__ __launch_bounds__(256) void k_ln(const float* __restrict__ ya, const float* __restrict__ yb,
                                            const float* __restrict__ g, const float* __restrict__ be,
                                            float* __restrict__ out){
  int i4 = blockIdx.x*256 + threadIdx.x;    // < 16*784
  int b = i4 / 784, p = (i4 % 784) * 4;
  const float* ap = ya + (size_t)b*CHW + p;
  const float* bp = yb + (size_t)b*CHW + p;
  float4 s = {0.f,0.f,0.f,0.f};
  for (int d = 0; d < 96; ++d){
    float4 av = *(const float4*)&ap[(size_t)d*Lpx];
    float4 bv = *(const float4*)&bp[(size_t)d*Lpx];
    s.x += av.x + bv.x; s.y += av.y + bv.y; s.z += av.z + bv.z; s.w += av.w + bv.w;
  }
  float4 mu; mu.x = s.x*(1.f/96.f); mu.y = s.y*(1.f/96.f); mu.z = s.z*(1.f/96.f); mu.w = s.w*(1.f/96.f);
  float4 ss = {0.f,0.f,0.f,0.f};
  for (int d = 0; d < 96; ++d){
    float4 av = *(const float4*)&ap[(size_t)d*Lpx];
    float4 bv = *(const float4*)&bp[(size_t)d*Lpx];
    float vx = av.x + bv.x - mu.x, vy = av.y + bv.y - mu.y;
    float vz = av.z + bv.z - mu.z, vw = av.w + bv.w - mu.w;
    ss.x = fmaf(vx,vx,ss.x); ss.y = fmaf(vy,vy,ss.y); ss.z = fmaf(vz,vz,ss.z); ss.w = fmaf(vw,vw,ss.w);
  }
  float4 rs;
  rs.x = 1.f/sqrtf(ss.x*(1.f/96.f) + 1e-5f); rs.y = 1.f/sqrtf(ss.y*(1.f/96.f) + 1e-5f);
  rs.z = 1.f/sqrtf(ss.z*(1.f/96.f) + 1e-5f); rs.w = 1.f/sqrtf(ss.w*(1.f/96.f) + 1e-5f);
  float* op = out + (size_t)b*CHW + p;
  for (int d = 0; d < 96; ++d){
    float4 av = *(const float4*)&ap[(size_t)d*Lpx];
    float4 bv = *(const float4*)&bp[(size_t)d*Lpx];
    float gd = g[d], bd = be[d];
    float4 o;
    o.x = (av.x + bv.x - mu.x)*rs.x*gd + bd;
    o.y = (av.y + bv.y - mu.y)*rs.y*gd + bd;
    o.z = (av.z + bv.z - mu.z)*rs.z*gd + bd;
    o.w = (av.w + bv.w - mu.w)*rs.w*gd + bd;
    *(float4*)&op[(size_t)d*Lpx] = o;
  }
}

// ---------------- LIF over T=4 + multiply with original x (float4) ----------------
__global__ __launch_bounds__(256) void k_lif2(const float* __restrict__ yo, const float* __restrict__ x0,
                                              float* __restrict__ out){
  const int stride4 = 301056;   // B*C*L/4
  int i4 = blockIdx.x*256 + threadIdx.x;
  float4 v = {0.f,0.f,0.f,0.f};
  #pragma unroll
  for (int t = 0; t < 4; ++t){
    float4 z = *(const float4*)&yo[((size_t)t*stride4 + i4)*4];
    float4 xv = *(const float4*)&x0[((size_t)t*stride4 + i4)*4];
    v.x = 0.5f*(v.x + z.x); v.y = 0.5f*(v.y + z.y);
    v.z = 0.5f*(v.z + z.z); v.w = 0.5f*(v.w + z.w);
    float4 o;
    o.x = (v.x >= 1.0f) ? xv.x : 0.f; o.y = (v.y >= 1.0f) ? xv.y : 0.f;
    o.z = (v.z >= 1.0f) ? xv.z : 0.f; o.w = (v.w >= 1.0f) ? xv.w : 0.f;
    v.x = (v.x >= 1.0f) ? 0.f : v.x; v.y = (v.y >= 1.0f) ? 0.f : v.y;
    v.z = (v.z >= 1.0f) ? 0.f : v.z; v.w = (v.w >= 1.0f) ? 0.f : v.w;
    *(float4*)&out[((size_t)t*stride4 + i4)*4] = o;
  }
}

extern "C" void kernel_launch(void* const* d_in, const int* in_sizes, int n_in,
                              void* d_out, int out_size, void* d_ws, size_t ws_size,
                              hipStream_t stream) {
  const float* x    = (const float*)d_in[0];
  const float* ipw  = (const float*)d_in[1];
  const float* ipb  = (const float*)d_in[2];
  const float* cw   = (const float*)d_in[3];
  const float* cb   = (const float*)d_in[4];
  const float* siw  = (const float*)d_in[5];
  const float* scw  = (const float*)d_in[6];
  const float* xpw  = (const float*)d_in[7];
  const float* dtw  = (const float*)d_in[8];
  const float* dtb  = (const float*)d_in[9];
  const float* alog = (const float*)d_in[10];
  const float* dsv  = (const float*)d_in[11];
  const float* lng  = (const float*)d_in[12];
  const float* lnb  = (const float*)d_in[13];
  const float* opw  = (const float*)d_in[14];

  float* s1 = (float*)d_ws;
  float* s2 = s1 + SZn;
  float* s3 = s2 + SZn;
  float* s4 = s3 + SZn;
  float* pr  = s4 + SZn;
  float* prT = pr + PRJ;

  // 1) in_proj -> xp in s1
  k_matmul<<<784, 256, 0, stream>>>(x, ipw, ipb, s1);
  // 2) LIF over 16 steps -> uchar spikes in s2
  k_lif1<<<294, 256, 0, stream>>>(s1, (unsigned char*)s2);
  // 3) dense 3x3 conv + bias + silu -> xc in s1
  k_conv4<<<dim3(16, 6, 14), 256, 0, stream>>>((const unsigned char*)s2, cw, cb, s1);
  // 4) ssm_in matmul -> s2
  k_matmul<<<784, 256, 0, stream>>>(s1, siw, nullptr, s2);
  // 5) depthwise conv + silu -> xss rm in s1, cm in s3
  k_dwconv<<<1536, 256, 0, stream>>>(s2, scw, s1, s3);
  // 6) projections (pixel-indexed, both layouts)
  k_proj<<<896, 256, 0, stream>>>(s1, xpw, pr, prT);
  // 7) both scan dir-pairs: ya -> s2, yb(row-major) -> s4
  k_scan2<<<dim3(1536, 2), 256, 0, stream>>>(s1, s3, pr, prT, dtw, dtb, alog, dsv, s2, s4);
  // 8) combine + LayerNorm -> s3
  k_ln<<<49, 256, 0, stream>>>(s2, s4, lng, lnb, s3);
  // 9) out_proj -> s2
  k_matmul<<<784, 256, 0, stream>>>(s3, opw, nullptr, s2);
  // 10) LIF over T=4, multiply with x -> d_out
  k_lif2<<<1176, 256, 0, stream>>>(s2, x, (float*)d_out);
}

// Round 10
// 616.889 us; speedup vs baseline: 1.6150x; 1.6150x over previous
//
#include <hip/hip_runtime.h>
#include <math.h>

#define TBn 16
#define Lpx 3136
#define CHW 301056      // 96*3136
#define SZn 4816896     // 16*96*3136
#define PRJ 1605632     // 16*32*3136
#define NPAD 3328       // 256*13

__device__ __forceinline__ float siluf_(float z){ return z / (1.f + expf(-z)); }
__device__ __forceinline__ float softplusf_(float z){ return fmaxf(z,0.f) + log1pf(expf(-fabsf(z))); }

// ---------------- per-pixel channel matmul v2: full weight tile, ci unrolled x4 ----------------
__global__ __launch_bounds__(256) void k_matmul(const float* __restrict__ in, const float* __restrict__ Wm,
                                                const float* __restrict__ bias, float* __restrict__ out){
  int blk = blockIdx.x;
  int n = blk / 49, pt = blk % 49, p0 = pt * 64;
  __shared__ float lx[96*64];     // [ci][px]  24.6KB
  __shared__ float wl[96*100];    // [co][ci], stride 100 (16B-aligned rows)  38.4KB
  int tid = threadIdx.x;
  const float* inb = in + (size_t)n*CHW;
  for (int i = tid; i < 96*64; i += 256){
    int ci = i >> 6, px = i & 63;
    lx[i] = inb[(size_t)ci*Lpx + p0 + px];
  }
  for (int i = tid; i < 96*96; i += 256){
    int co = i / 96, ci = i % 96;
    wl[co*100 + ci] = Wm[i];
  }
  int px_t = tid & 15, co_t = tid >> 4;   // px base px_t*4, co base co_t*6
  float acc[6][4];
  #pragma unroll
  for (int j = 0; j < 6; ++j){
    float b = bias ? bias[co_t*6 + j] : 0.f;
    #pragma unroll
    for (int q = 0; q < 4; ++q) acc[j][q] = b;
  }
  __syncthreads();
  for (int c4 = 0; c4 < 24; ++c4){
    float4 xv0 = *(const float4*)&lx[(c4*4 + 0)*64 + px_t*4];
    float4 xv1 = *(const float4*)&lx[(c4*4 + 1)*64 + px_t*4];
    float4 xv2 = *(const float4*)&lx[(c4*4 + 2)*64 + px_t*4];
    float4 xv3 = *(const float4*)&lx[(c4*4 + 3)*64 + px_t*4];
    #pragma unroll
    for (int j = 0; j < 6; ++j){
      float4 wv = *(const float4*)&wl[(co_t*6 + j)*100 + c4*4];
      acc[j][0] = fmaf(wv.x, xv0.x, acc[j][0]); acc[j][1] = fmaf(wv.x, xv0.y, acc[j][1]);
      acc[j][2] = fmaf(wv.x, xv0.z, acc[j][2]); acc[j][3] = fmaf(wv.x, xv0.w, acc[j][3]);
      acc[j][0] = fmaf(wv.y, xv1.x, acc[j][0]); acc[j][1] = fmaf(wv.y, xv1.y, acc[j][1]);
      acc[j][2] = fmaf(wv.y, xv1.z, acc[j][2]); acc[j][3] = fmaf(wv.y, xv1.w, acc[j][3]);
      acc[j][0] = fmaf(wv.z, xv2.x, acc[j][0]); acc[j][1] = fmaf(wv.z, xv2.y, acc[j][1]);
      acc[j][2] = fmaf(wv.z, xv2.z, acc[j][2]); acc[j][3] = fmaf(wv.z, xv2.w, acc[j][3]);
      acc[j][0] = fmaf(wv.w, xv3.x, acc[j][0]); acc[j][1] = fmaf(wv.w, xv3.y, acc[j][1]);
      acc[j][2] = fmaf(wv.w, xv3.z, acc[j][2]); acc[j][3] = fmaf(wv.w, xv3.w, acc[j][3]);
    }
  }
  float* ob = out + (size_t)n*CHW + p0 + px_t*4;
  #pragma unroll
  for (int j = 0; j < 6; ++j){
    float4 v; v.x = acc[j][0]; v.y = acc[j][1]; v.z = acc[j][2]; v.w = acc[j][3];
    *(float4*)&ob[(size_t)(co_t*6 + j)*Lpx] = v;
  }
}

// ---------------- LIF over 16 steps, float4, uchar spike output ----------------
__global__ __launch_bounds__(256) void k_lif1(const float* __restrict__ xp, unsigned char* __restrict__ sp){
  int i4 = blockIdx.x*256 + threadIdx.x;     // < CHW/4
  float4 v = {0.f,0.f,0.f,0.f};
  #pragma unroll
  for (int t = 0; t < 16; ++t){
    float4 z = *(const float4*)&xp[(size_t)t*CHW + (size_t)i4*4];
    v.x = 0.5f*(v.x + z.x); v.y = 0.5f*(v.y + z.y);
    v.z = 0.5f*(v.z + z.z); v.w = 0.5f*(v.w + z.w);
    uchar4 s;
    s.x = (v.x >= 1.0f); s.y = (v.y >= 1.0f); s.z = (v.z >= 1.0f); s.w = (v.w >= 1.0f);
    *(uchar4*)&sp[(size_t)t*CHW + (size_t)i4*4] = s;
    v.x = s.x ? 0.f : v.x; v.y = s.y ? 0.f : v.y;
    v.z = s.z ? 0.f : v.z; v.w = s.w ? 0.f : v.w;
  }
}

// ---------------- dense 3x3 conv (96->96) + bias + silu, v5 ----------------
// thread tile: 4 co x 1 h x 8 w -> 288 FMA per ci vs 18 LDS instr (LDS-issue halved per FLOP).
// block: 16 co x 8 h x 56 w; 224 active threads; CIC=8 -> 23.8 KB LDS; grid (16,6,7).
#define CIC3 8
__global__ __launch_bounds__(256) void k_conv5(const unsigned char* __restrict__ spk, const float* __restrict__ cw,
                                               const float* __restrict__ cb, float* __restrict__ out){
  int b = blockIdx.x, cog = blockIdx.y, hb = blockIdx.z;
  int co0 = cog*16, h0 = hb*8;
  int tid = threadIdx.x;
  int hl = tid / 28, rem2 = tid % 28;
  int coh = rem2 / 7, wq = rem2 % 7;         // active if tid < 224
  bool act = tid < 224;
  __shared__ float xl[CIC3*10*60];           // [ci][row 0..9][col 0..57, stride 60]
  __shared__ float wl[CIC3*9*16];            // [ci][tap][co]
  float acc[4][8];
  #pragma unroll
  for (int j = 0; j < 4; ++j)
    #pragma unroll
    for (int q = 0; q < 8; ++q) acc[j][q] = 0.f;

  for (int cc = 0; cc < 12; ++cc){
    __syncthreads();
    for (int i = tid; i < CIC3*10*58; i += 256){
      int ci = i / 580, rem = i % 580;
      int hh = rem / 58, ww = rem % 58;
      int sh = h0 - 1 + hh, sw = ww - 1;
      float v = 0.f;
      if (sh >= 0 && sh < 56 && sw >= 0 && sw < 56)
        v = (float)spk[(((size_t)b*96 + cc*CIC3 + ci)*56 + sh)*56 + sw];
      xl[ci*600 + hh*60 + ww] = v;
    }
    for (int i = tid; i < CIC3*9*16; i += 256){
      int ci = i / 144, rem = i % 144;
      int tap = rem / 16, co = rem % 16;
      wl[i] = cw[(((size_t)(co0+co))*96 + cc*CIC3 + ci)*9 + tap];
    }
    __syncthreads();
    if (act){
      for (int ci = 0; ci < CIC3; ++ci){
        float xr[3][10];
        int base = ci*600 + hl*60 + wq*8;
        #pragma unroll
        for (int dh = 0; dh < 3; ++dh){
          float4 a = *(const float4*)&xl[base + dh*60];
          float4 c = *(const float4*)&xl[base + dh*60 + 4];
          float2 e = *(const float2*)&xl[base + dh*60 + 8];
          xr[dh][0] = a.x; xr[dh][1] = a.y; xr[dh][2] = a.z; xr[dh][3] = a.w;
          xr[dh][4] = c.x; xr[dh][5] = c.y; xr[dh][6] = c.z; xr[dh][7] = c.w;
          xr[dh][8] = e.x; xr[dh][9] = e.y;
        }
        #pragma unroll
        for (int tap = 0; tap < 9; ++tap){
          const int dh = tap/3, dw = tap%3;
          float4 w = *(const float4*)&wl[(ci*9 + tap)*16 + coh*4];
          #pragma unroll
          for (int q = 0; q < 8; ++q){
            float xv = xr[dh][q + dw];
            acc[0][q] = fmaf(xv, w.x, acc[0][q]);
            acc[1][q] = fmaf(xv, w.y, acc[1][q]);
            acc[2][q] = fmaf(xv, w.z, acc[2][q]);
            acc[3][q] = fmaf(xv, w.w, acc[3][q]);
          }
        }
      }
    }
  }
  if (act){
    #pragma unroll
    for (int j = 0; j < 4; ++j){
      int co = co0 + coh*4 + j;
      float bv = cb[co];
      float4 o0, o1;
      o0.x = siluf_(acc[j][0] + bv); o0.y = siluf_(acc[j][1] + bv);
      o0.z = siluf_(acc[j][2] + bv); o0.w = siluf_(acc[j][3] + bv);
      o1.x = siluf_(acc[j][4] + bv); o1.y = siluf_(acc[j][5] + bv);
      o1.z = siluf_(acc[j][6] + bv); o1.w = siluf_(acc[j][7] + bv);
      float* op = &out[(((size_t)b*96 + co)*56 + h0 + hl)*56 + wq*8];
      *(float4*)op = o0;
      *(float4*)(op + 4) = o1;
    }
  }
}

// ---------------- depthwise 3x3 + silu, writes row-major and transposed ----------------
__global__ __launch_bounds__(256) void k_dwconv(const float* __restrict__ xin, const float* __restrict__ dwW,
                                                float* __restrict__ out, float* __restrict__ outT){
  int bd = blockIdx.x;           // b*96+d
  int d = bd % 96;
  const float* ip = xin + (size_t)bd*Lpx;
  __shared__ float pl[Lpx];
  __shared__ float po[Lpx + 56];
  int tid = threadIdx.x;
  for (int i = tid; i < Lpx; i += 256) pl[i] = ip[i];
  float w9[9];
  #pragma unroll
  for (int t = 0; t < 9; ++t) w9[t] = dwW[d*9 + t];
  __syncthreads();
  for (int i = tid; i < Lpx; i += 256){
    int h = i / 56, w = i % 56;
    float s = 0.f;
    #pragma unroll
    for (int tap = 0; tap < 9; ++tap){
      int hh = h + tap/3 - 1, ww = w + tap%3 - 1;
      if (hh >= 0 && hh < 56 && ww >= 0 && ww < 56) s = fmaf(pl[hh*56 + ww], w9[tap], s);
    }
    po[i + i/56] = siluf_(s);
  }
  __syncthreads();
  float* op  = out  + (size_t)bd*Lpx;
  float* otp = outT + (size_t)bd*Lpx;
  for (int i = tid; i < Lpx; i += 256){
    op[i] = po[i + i/56];
    int q = (i % 56)*56 + i/56;
    otp[i] = po[q + q/56];        // stride-57 LDS read: conflict-free
  }
}

// ---------------- per-pixel 96->(4k x 8r) projections, row-major and transposed ----------------
__global__ __launch_bounds__(256) void k_proj(const float* __restrict__ xss, const float* __restrict__ xpw,
                                              float* __restrict__ PROJ, float* __restrict__ PROJT){
  int b = blockIdx.x / 56, h = blockIdx.x % 56;
  __shared__ float lx[96*56];    // [d][w]
  __shared__ float lw[32*96];    // [kr][d]
  int tid = threadIdx.x;
  const float* xb = xss + (size_t)b*CHW + h*56;
  for (int i = tid; i < 96*56; i += 256){
    int d = i / 56, w = i % 56;
    lx[i] = xb[(size_t)d*Lpx + w];
  }
  for (int i = tid; i < 32*96; i += 256) lw[i] = xpw[i];
  __syncthreads();
  for (int o = tid; o < 32*56; o += 256){
    int w = o % 56, kr = o / 56;
    float s = 0.f;
    for (int d = 0; d < 96; ++d) s = fmaf(lx[d*56 + w], lw[kr*96 + d], s);
    size_t base = ((size_t)b*32 + kr)*Lpx;
    PROJ[base + h*56 + w] = s;
    PROJT[base + w*56 + h] = s;
  }
}

// ---------------- block-parallel bidirectional selective scan ----------------
__global__ __launch_bounds__(256) void k_scan2(const float* __restrict__ x_rm, const float* __restrict__ x_cm,
                                               const float* __restrict__ PROJ, const float* __restrict__ PROJT,
                                               const float* __restrict__ dtw_all, const float* __restrict__ dtb_all,
                                               const float* __restrict__ Alog, const float* __restrict__ Dall,
                                               float* __restrict__ out0, float* __restrict__ out1){
  int bd = blockIdx.x; int b = bd / 96, d = bd % 96;
  int klo = blockIdx.y;
  const float* xv = (klo == 0 ? x_rm : x_cm) + (size_t)bd*Lpx;
  const float* PR = (klo == 0 ? PROJ : PROJT);
  float* yo = (klo == 0 ? out0 : out1) + (size_t)bd*Lpx;
  int kA = klo, kB = klo + 2;

  float dwA[6], dwB[6];
  #pragma unroll
  for (int r = 0; r < 6; ++r){ dwA[r] = dtw_all[(kA*96 + d)*6 + r]; dwB[r] = dtw_all[(kB*96 + d)*6 + r]; }
  float biA = dtb_all[kA*96 + d], biB = dtb_all[kB*96 + d];
  float AA = -expf(Alog[kA*96 + d]), AB = -expf(Alog[kB*96 + d]);
  float Dsum = Dall[kA*96 + d] + Dall[kB*96 + d];
  const float* pA = PR + ((size_t)b*32 + kA*8)*Lpx;
  const float* pB = PR + ((size_t)b*32 + kB*8)*Lpx;

  __shared__ float xb[Lpx];
  __shared__ float u[NPAD];
  __shared__ float v[NPAD];
  __shared__ float yacc[Lpx + 56];
  __shared__ float wag[8];

  int tid = threadIdx.x;
  int lane = tid & 63, wv = tid >> 6;
  int base = tid * 13;

  for (int i = tid; i < Lpx; i += 256) xb[i] = xv[i];

  // ======== direction A (forward in p) ========
  for (int i = tid; i < Lpx; i += 256){
    float z = biA;
    #pragma unroll
    for (int r = 0; r < 6; ++r) z = fmaf(dwA[r], pA[(size_t)r*Lpx + i], z);
    float dt = softplusf_(z);
    u[i] = expf(dt * AA);
    v[i] = dt * pA[(size_t)6*Lpx + i] * xb[i];
  }
  for (int i = Lpx + tid; i < NPAD; i += 256){ u[i] = 1.f; v[i] = 0.f; }
  __syncthreads();

  {
    float a = 1.f, bb = 0.f;
    #pragma unroll
    for (int j = 0; j < 13; ++j){
      float da = u[base + j], db = v[base + j];
      bb = fmaf(da, bb, db);
      a *= da;
      u[base + j] = a; v[base + j] = bb;
    }
    float aT = a, bT = bb;
    #pragma unroll
    for (int off = 1; off < 64; off <<= 1){
      float ap = __shfl_up(aT, off), bp = __shfl_up(bT, off);
      if (lane >= off){ bT = fmaf(aT, bp, bT); aT *= ap; }
    }
    if (lane == 63){ wag[wv] = aT; wag[4 + wv] = bT; }
    float a_ex = __shfl_up(aT, 1), b_ex = __shfl_up(bT, 1);
    if (lane == 0){ a_ex = 1.f; b_ex = 0.f; }
    __syncthreads();
    float hw = 0.f;
    for (int j = 0; j < wv; ++j) hw = fmaf(wag[j], hw, wag[4 + j]);
    float hin = fmaf(a_ex, hw, b_ex);
    #pragma unroll
    for (int j = 0; j < 13; ++j)
      v[base + j] = fmaf(u[base + j], hin, v[base + j]);
  }
  __syncthreads();
  for (int i = tid; i < Lpx; i += 256){
    float C = pA[(size_t)7*Lpx + i];
    yacc[i + i/56] = fmaf(C, v[i], Dsum * xb[i]);
  }
  __syncthreads();

  // ======== direction B (reverse in p) ========
  for (int i = tid; i < Lpx; i += 256){
    float z = biB;
    #pragma unroll
    for (int r = 0; r < 6; ++r) z = fmaf(dwB[r], pB[(size_t)r*Lpx + i], z);
    float dt = softplusf_(z);
    u[i] = expf(dt * AB);
    v[i] = dt * pB[(size_t)6*Lpx + i] * xb[i];
  }
  for (int i = Lpx + tid; i < NPAD; i += 256){ u[i] = 1.f; v[i] = 0.f; }
  __syncthreads();

  {
    float a = 1.f, bb = 0.f;
    #pragma unroll
    for (int j = 12; j >= 0; --j){
      float da = u[base + j], db = v[base + j];
      bb = fmaf(da, bb, db);
      a *= da;
      u[base + j] = a; v[base + j] = bb;
    }
    float aT = a, bT = bb;
    #pragma unroll
    for (int off = 1; off < 64; off <<= 1){
      float ap = __shfl_down(aT, off), bp = __shfl_down(bT, off);
      if (lane + off < 64){ bT = fmaf(aT, bp, bT); aT *= ap; }
    }
    if (lane == 0){ wag[wv] = aT; wag[4 + wv] = bT; }
    float a_ex = __shfl_down(aT, 1), b_ex = __shfl_down(bT, 1);
    if (lane == 63){ a_ex = 1.f; b_ex = 0.f; }
    __syncthreads();
    float hw = 0.f;
    for (int j = 3; j > wv; --j) hw = fmaf(wag[j], hw, wag[4 + j]);
    float hin = fmaf(a_ex, hw, b_ex);
    #pragma unroll
    for (int j = 0; j < 13; ++j)
      v[base + j] = fmaf(u[base + j], hin, v[base + j]);
  }
  __syncthreads();
  for (int i = tid; i < Lpx; i += 256){
    float C = pB[(size_t)7*Lpx + i];
    yacc[i + i/56] = fmaf(C, v[i], yacc[i + i/56]);
  }
  __syncthreads();

  if (klo == 0){
    for (int i = tid; i < Lpx; i += 256)
      yo[i] = yacc[i + i/56];
  } else {
    for (int i = tid; i < Lpx; i += 256){
      int q = (i % 56)*56 + i/56;
      yo[i] = yacc[q + q/56];
    }
  }
}

// ---------------- combine ya+yb, LayerNorm over channels (float4) ----------------
__global__ __launch_bounds__(256) void k_ln(const float* __restrict__ ya, const float* __restrict__ yb,
                                            const float* __restrict__ g, const float* __restrict__ be,
                                            float* __restrict__ out){
  int i4 = blockIdx.x*256 + threadIdx.x;    // < 16*784
  int b = i4 / 784, p = (i4 % 784) * 4;
  const float* ap = ya + (size_t)b*CHW + p;
  const float* bp = yb + (size_t)b*CHW + p;
  float4 s = {0.f,0.f,0.f,0.f};
  for (int d = 0; d < 96; ++d){
    float4 av = *(const float4*)&ap[(size_t)d*Lpx];
    float4 bv = *(const float4*)&bp[(size_t)d*Lpx];
    s.x += av.x + bv.x; s.y += av.y + bv.y; s.z += av.z + bv.z; s.w += av.w + bv.w;
  }
  float4 mu; mu.x = s.x*(1.f/96.f); mu.y = s.y*(1.f/96.f); mu.z = s.z*(1.f/96.f); mu.w = s.w*(1.f/96.f);
  float4 ss = {0.f,0.f,0.f,0.f};
  for (int d = 0; d < 96; ++d){
    float4 av = *(const float4*)&ap[(size_t)d*Lpx];
    float4 bv = *(const float4*)&bp[(size_t)d*Lpx];
    float vx = av.x + bv.x - mu.x, vy = av.y + bv.y - mu.y;
    float vz = av.z + bv.z - mu.z, vw = av.w + bv.w - mu.w;
    ss.x = fmaf(vx,vx,ss.x); ss.y = fmaf(vy,vy,ss.y); ss.z = fmaf(vz,vz,ss.z); ss.w = fmaf(vw,vw,ss.w);
  }
  float4 rs;
  rs.x = 1.f/sqrtf(ss.x*(1.f/96.f) + 1e-5f); rs.y = 1.f/sqrtf(ss.y*(1.f/96.f) + 1e-5f);
  rs.z = 1.f/sqrtf(ss.z*(1.f/96.f) + 1e-5f); rs.w = 1.f/sqrtf(ss.w*(1.f/96.f) + 1e-5f);
  float* op = out + (size_t)b*CHW + p;
  for (int d = 0; d < 96; ++d){
    float4 av = *(const float4*)&ap[(size_t)d*Lpx];
    float4 bv = *(const float4*)&bp[(size_t)d*Lpx];
    float gd = g[d], bd = be[d];
    float4 o;
    o.x = (av.x + bv.x - mu.x)*rs.x*gd + bd;
    o.y = (av.y + bv.y - mu.y)*rs.y*gd + bd;
    o.z = (av.z + bv.z - mu.z)*rs.z*gd + bd;
    o.w = (av.w + bv.w - mu.w)*rs.w*gd + bd;
    *(float4*)&op[(size_t)d*Lpx] = o;
  }
}

// ---------------- LIF over T=4 + multiply with original x (float4) ----------------
__global__ __launch_bounds__(256) void k_lif2(const float* __restrict__ yo, const float* __restrict__ x0,
                                              float* __restrict__ out){
  const int stride4 = 301056;   // B*C*L/4
  int i4 = blockIdx.x*256 + threadIdx.x;
  float4 v = {0.f,0.f,0.f,0.f};
  #pragma unroll
  for (int t = 0; t < 4; ++t){
    float4 z = *(const float4*)&yo[((size_t)t*stride4 + i4)*4];
    float4 xv = *(const float4*)&x0[((size_t)t*stride4 + i4)*4];
    v.x = 0.5f*(v.x + z.x); v.y = 0.5f*(v.y + z.y);
    v.z = 0.5f*(v.z + z.z); v.w = 0.5f*(v.w + z.w);
    float4 o;
    o.x = (v.x >= 1.0f) ? xv.x : 0.f; o.y = (v.y >= 1.0f) ? xv.y : 0.f;
    o.z = (v.z >= 1.0f) ? xv.z : 0.f; o.w = (v.w >= 1.0f) ? xv.w : 0.f;
    v.x = (v.x >= 1.0f) ? 0.f : v.x; v.y = (v.y >= 1.0f) ? 0.f : v.y;
    v.z = (v.z >= 1.0f) ? 0.f : v.z; v.w = (v.w >= 1.0f) ? 0.f : v.w;
    *(float4*)&out[((size_t)t*stride4 + i4)*4] = o;
  }
}

extern "C" void kernel_launch(void* const* d_in, const int* in_sizes, int n_in,
                              void* d_out, int out_size, void* d_ws, size_t ws_size,
                              hipStream_t stream) {
  const float* x    = (const float*)d_in[0];
  const float* ipw  = (const float*)d_in[1];
  const float* ipb  = (const float*)d_in[2];
  const float* cw   = (const float*)d_in[3];
  const float* cb   = (const float*)d_in[4];
  const float* siw  = (const float*)d_in[5];
  const float* scw  = (const float*)d_in[6];
  const float* xpw  = (const float*)d_in[7];
  const float* dtw  = (const float*)d_in[8];
  const float* dtb  = (const float*)d_in[9];
  const float* alog = (const float*)d_in[10];
  const float* dsv  = (const float*)d_in[11];
  const float* lng  = (const float*)d_in[12];
  const float* lnb  = (const float*)d_in[13];
  const float* opw  = (const float*)d_in[14];

  float* s1 = (float*)d_ws;
  float* s2 = s1 + SZn;
  float* s3 = s2 + SZn;
  float* s4 = s3 + SZn;
  float* pr  = s4 + SZn;
  float* prT = pr + PRJ;

  // 1) in_proj -> xp in s1
  k_matmul<<<784, 256, 0, stream>>>(x, ipw, ipb, s1);
  // 2) LIF over 16 steps -> uchar spikes in s2
  k_lif1<<<294, 256, 0, stream>>>(s1, (unsigned char*)s2);
  // 3) dense 3x3 conv + bias + silu -> xc in s1
  k_conv5<<<dim3(16, 6, 7), 256, 0, stream>>>((const unsigned char*)s2, cw, cb, s1);
  // 4) ssm_in matmul -> s2
  k_matmul<<<784, 256, 0, stream>>>(s1, siw, nullptr, s2);
  // 5) depthwise conv + silu -> xss rm in s1, cm in s3
  k_dwconv<<<1536, 256, 0, stream>>>(s2, scw, s1, s3);
  // 6) projections (pixel-indexed, both layouts)
  k_proj<<<896, 256, 0, stream>>>(s1, xpw, pr, prT);
  // 7) both scan dir-pairs: ya -> s2, yb(row-major) -> s4
  k_scan2<<<dim3(1536, 2), 256, 0, stream>>>(s1, s3, pr, prT, dtw, dtb, alog, dsv, s2, s4);
  // 8) combine + LayerNorm -> s3
  k_ln<<<49, 256, 0, stream>>>(s2, s4, lng, lnb, s3);
  // 9) out_proj -> s2
  k_matmul<<<784, 256, 0, stream>>>(s3, opw, nullptr, s2);
  // 10) LIF over T=4, multiply with x -> d_out
  k_lif2<<<1176, 256, 0, stream>>>(s2, x, (float*)d_out);
}

// Round 11
// 579.841 us; speedup vs baseline: 1.7182x; 1.0639x over previous
//
#include <hip/hip_runtime.h>
#include <math.h>

#define TBn 16
#define Lpx 3136
#define CHW 301056      // 96*3136
#define SZn 4816896     // 16*96*3136
#define PRJ 1605632     // 16*32*3136
#define NPAD 3328       // 256*13

__device__ __forceinline__ float siluf_(float z){ return z / (1.f + expf(-z)); }
__device__ __forceinline__ float softplusf_(float z){ return fmaxf(z,0.f) + log1pf(expf(-fabsf(z))); }

// ---------------- per-pixel channel matmul v2: full weight tile, ci unrolled x4 ----------------
__global__ __launch_bounds__(256) void k_matmul(const float* __restrict__ in, const float* __restrict__ Wm,
                                                const float* __restrict__ bias, float* __restrict__ out){
  int blk = blockIdx.x;
  int n = blk / 49, pt = blk % 49, p0 = pt * 64;
  __shared__ float lx[96*64];     // [ci][px]
  __shared__ float wl[96*100];    // [co][ci], stride 100
  int tid = threadIdx.x;
  const float* inb = in + (size_t)n*CHW;
  for (int i = tid; i < 96*64; i += 256){
    int ci = i >> 6, px = i & 63;
    lx[i] = inb[(size_t)ci*Lpx + p0 + px];
  }
  for (int i = tid; i < 96*96; i += 256){
    int co = i / 96, ci = i % 96;
    wl[co*100 + ci] = Wm[i];
  }
  int px_t = tid & 15, co_t = tid >> 4;
  float acc[6][4];
  #pragma unroll
  for (int j = 0; j < 6; ++j){
    float b = bias ? bias[co_t*6 + j] : 0.f;
    #pragma unroll
    for (int q = 0; q < 4; ++q) acc[j][q] = b;
  }
  __syncthreads();
  for (int c4 = 0; c4 < 24; ++c4){
    float4 xv0 = *(const float4*)&lx[(c4*4 + 0)*64 + px_t*4];
    float4 xv1 = *(const float4*)&lx[(c4*4 + 1)*64 + px_t*4];
    float4 xv2 = *(const float4*)&lx[(c4*4 + 2)*64 + px_t*4];
    float4 xv3 = *(const float4*)&lx[(c4*4 + 3)*64 + px_t*4];
    #pragma unroll
    for (int j = 0; j < 6; ++j){
      float4 wv = *(const float4*)&wl[(co_t*6 + j)*100 + c4*4];
      acc[j][0] = fmaf(wv.x, xv0.x, acc[j][0]); acc[j][1] = fmaf(wv.x, xv0.y, acc[j][1]);
      acc[j][2] = fmaf(wv.x, xv0.z, acc[j][2]); acc[j][3] = fmaf(wv.x, xv0.w, acc[j][3]);
      acc[j][0] = fmaf(wv.y, xv1.x, acc[j][0]); acc[j][1] = fmaf(wv.y, xv1.y, acc[j][1]);
      acc[j][2] = fmaf(wv.y, xv1.z, acc[j][2]); acc[j][3] = fmaf(wv.y, xv1.w, acc[j][3]);
      acc[j][0] = fmaf(wv.z, xv2.x, acc[j][0]); acc[j][1] = fmaf(wv.z, xv2.y, acc[j][1]);
      acc[j][2] = fmaf(wv.z, xv2.z, acc[j][2]); acc[j][3] = fmaf(wv.z, xv2.w, acc[j][3]);
      acc[j][0] = fmaf(wv.w, xv3.x, acc[j][0]); acc[j][1] = fmaf(wv.w, xv3.y, acc[j][1]);
      acc[j][2] = fmaf(wv.w, xv3.z, acc[j][2]); acc[j][3] = fmaf(wv.w, xv3.w, acc[j][3]);
    }
  }
  float* ob = out + (size_t)n*CHW + p0 + px_t*4;
  #pragma unroll
  for (int j = 0; j < 6; ++j){
    float4 v; v.x = acc[j][0]; v.y = acc[j][1]; v.z = acc[j][2]; v.w = acc[j][3];
    *(float4*)&ob[(size_t)(co_t*6 + j)*Lpx] = v;
  }
}

// ---------------- matmul merge variant: in = silu(pA+pB+cb), no matmul bias ----------------
__global__ __launch_bounds__(256) void k_matmulM(const float* __restrict__ pA, const float* __restrict__ pB,
                                                 const float* __restrict__ cbias, const float* __restrict__ Wm,
                                                 float* __restrict__ out){
  int blk = blockIdx.x;
  int n = blk / 49, pt = blk % 49, p0 = pt * 64;
  __shared__ float lx[96*64];
  __shared__ float wl[96*100];
  int tid = threadIdx.x;
  const float* inA = pA + (size_t)n*CHW;
  const float* inB = pB + (size_t)n*CHW;
  for (int i = tid; i < 96*64; i += 256){
    int ci = i >> 6, px = i & 63;
    float z = inA[(size_t)ci*Lpx + p0 + px] + inB[(size_t)ci*Lpx + p0 + px] + cbias[ci];
    lx[i] = siluf_(z);
  }
  for (int i = tid; i < 96*96; i += 256){
    int co = i / 96, ci = i % 96;
    wl[co*100 + ci] = Wm[i];
  }
  int px_t = tid & 15, co_t = tid >> 4;
  float acc[6][4];
  #pragma unroll
  for (int j = 0; j < 6; ++j)
    #pragma unroll
    for (int q = 0; q < 4; ++q) acc[j][q] = 0.f;
  __syncthreads();
  for (int c4 = 0; c4 < 24; ++c4){
    float4 xv0 = *(const float4*)&lx[(c4*4 + 0)*64 + px_t*4];
    float4 xv1 = *(const float4*)&lx[(c4*4 + 1)*64 + px_t*4];
    float4 xv2 = *(const float4*)&lx[(c4*4 + 2)*64 + px_t*4];
    float4 xv3 = *(const float4*)&lx[(c4*4 + 3)*64 + px_t*4];
    #pragma unroll
    for (int j = 0; j < 6; ++j){
      float4 wv = *(const float4*)&wl[(co_t*6 + j)*100 + c4*4];
      acc[j][0] = fmaf(wv.x, xv0.x, acc[j][0]); acc[j][1] = fmaf(wv.x, xv0.y, acc[j][1]);
      acc[j][2] = fmaf(wv.x, xv0.z, acc[j][2]); acc[j][3] = fmaf(wv.x, xv0.w, acc[j][3]);
      acc[j][0] = fmaf(wv.y, xv1.x, acc[j][0]); acc[j][1] = fmaf(wv.y, xv1.y, acc[j][1]);
      acc[j][2] = fmaf(wv.y, xv1.z, acc[j][2]); acc[j][3] = fmaf(wv.y, xv1.w, acc[j][3]);
      acc[j][0] = fmaf(wv.z, xv2.x, acc[j][0]); acc[j][1] = fmaf(wv.z, xv2.y, acc[j][1]);
      acc[j][2] = fmaf(wv.z, xv2.z, acc[j][2]); acc[j][3] = fmaf(wv.z, xv2.w, acc[j][3]);
      acc[j][0] = fmaf(wv.w, xv3.x, acc[j][0]); acc[j][1] = fmaf(wv.w, xv3.y, acc[j][1]);
      acc[j][2] = fmaf(wv.w, xv3.z, acc[j][2]); acc[j][3] = fmaf(wv.w, xv3.w, acc[j][3]);
    }
  }
  float* ob = out + (size_t)n*CHW + p0 + px_t*4;
  #pragma unroll
  for (int j = 0; j < 6; ++j){
    float4 v; v.x = acc[j][0]; v.y = acc[j][1]; v.z = acc[j][2]; v.w = acc[j][3];
    *(float4*)&ob[(size_t)(co_t*6 + j)*Lpx] = v;
  }
}

// ---------------- LIF over 16 steps, float4, uchar spike output ----------------
__global__ __launch_bounds__(256) void k_lif1(const float* __restrict__ xp, unsigned char* __restrict__ sp){
  int i4 = blockIdx.x*256 + threadIdx.x;     // < CHW/4
  float4 v = {0.f,0.f,0.f,0.f};
  #pragma unroll
  for (int t = 0; t < 16; ++t){
    float4 z = *(const float4*)&xp[(size_t)t*CHW + (size_t)i4*4];
    v.x = 0.5f*(v.x + z.x); v.y = 0.5f*(v.y + z.y);
    v.z = 0.5f*(v.z + z.z); v.w = 0.5f*(v.w + z.w);
    uchar4 s;
    s.x = (v.x >= 1.0f); s.y = (v.y >= 1.0f); s.z = (v.z >= 1.0f); s.w = (v.w >= 1.0f);
    *(uchar4*)&sp[(size_t)t*CHW + (size_t)i4*4] = s;
    v.x = s.x ? 0.f : v.x; v.y = s.y ? 0.f : v.y;
    v.z = s.z ? 0.f : v.z; v.w = s.w ? 0.f : v.w;
  }
}

// ---------------- dense 3x3 conv v6: SGPR weights (wave-uniform co-quad) + K-split ----------------
// wave w -> co quad; lane = hl*8 + wq (wq<7 active). Block: 16co x 8h x 56w, 6 cc-chunks.
// blockIdx.y = cog + 6*ks. ks0 -> outP0, ks1 -> outP1 (raw partials, no bias/silu).
#define CIC3 8
__global__ __launch_bounds__(256) void k_conv6(const unsigned char* __restrict__ spk, const float* __restrict__ cw,
                                               float* __restrict__ outP0, float* __restrict__ outP1){
  int b = blockIdx.x;
  int cog = blockIdx.y % 6, ks = blockIdx.y / 6;
  int hb = blockIdx.z;
  int co0 = cog*16, h0 = hb*8;
  int tid = threadIdx.x;
  int wid = tid >> 6, lane = tid & 63;
  int hl = lane >> 3, wq = lane & 7;         // wq<7 active
  int coq = __builtin_amdgcn_readfirstlane(wid);
  __shared__ float xl[CIC3*10*68];           // [ci][row 0..9][col, stride 68]
  float acc[4][8];
  #pragma unroll
  for (int j = 0; j < 4; ++j)
    #pragma unroll
    for (int q = 0; q < 8; ++q) acc[j][q] = 0.f;

  for (int cc = ks*6; cc < ks*6 + 6; ++cc){
    __syncthreads();
    for (int i = tid; i < CIC3*10*58; i += 256){
      int ci = i / 580, rem = i % 580;
      int hh = rem / 58, ww = rem % 58;
      int sh = h0 - 1 + hh, sw = ww - 1;
      float v = 0.f;
      if (sh >= 0 && sh < 56 && sw >= 0 && sw < 56)
        v = (float)spk[(((size_t)b*96 + cc*CIC3 + ci)*56 + sh)*56 + sw];
      xl[ci*680 + hh*68 + ww] = v;
    }
    __syncthreads();
    for (int ci = 0; ci < CIC3; ++ci){
      int cig = cc*CIC3 + ci;
      // wave-uniform weight loads -> SGPRs
      float wj[9][4];
      #pragma unroll
      for (int tap = 0; tap < 9; ++tap)
        #pragma unroll
        for (int j = 0; j < 4; ++j)
          wj[tap][j] = cw[(((size_t)(co0 + coq*4 + j))*96 + cig)*9 + tap];
      float xr[3][10];
      int base = ci*680 + hl*68 + wq*8;
      #pragma unroll
      for (int dh = 0; dh < 3; ++dh){
        float4 a = *(const float4*)&xl[base + dh*68];
        float4 c = *(const float4*)&xl[base + dh*68 + 4];
        float2 e = *(const float2*)&xl[base + dh*68 + 8];
        xr[dh][0] = a.x; xr[dh][1] = a.y; xr[dh][2] = a.z; xr[dh][3] = a.w;
        xr[dh][4] = c.x; xr[dh][5] = c.y; xr[dh][6] = c.z; xr[dh][7] = c.w;
        xr[dh][8] = e.x; xr[dh][9] = e.y;
      }
      #pragma unroll
      for (int tap = 0; tap < 9; ++tap){
        const int dh = tap/3, dw = tap%3;
        #pragma unroll
        for (int q = 0; q < 8; ++q){
          float xv = xr[dh][q + dw];
          acc[0][q] = fmaf(xv, wj[tap][0], acc[0][q]);
          acc[1][q] = fmaf(xv, wj[tap][1], acc[1][q]);
          acc[2][q] = fmaf(xv, wj[tap][2], acc[2][q]);
          acc[3][q] = fmaf(xv, wj[tap][3], acc[3][q]);
        }
      }
    }
  }
  if (wq < 7){
    float* outp = (ks == 0) ? outP0 : outP1;
    #pragma unroll
    for (int j = 0; j < 4; ++j){
      int co = co0 + coq*4 + j;
      float4 o0, o1;
      o0.x = acc[j][0]; o0.y = acc[j][1]; o0.z = acc[j][2]; o0.w = acc[j][3];
      o1.x = acc[j][4]; o1.y = acc[j][5]; o1.z = acc[j][6]; o1.w = acc[j][7];
      float* op = &outp[(((size_t)b*96 + co)*56 + h0 + hl)*56 + wq*8];
      *(float4*)op = o0;
      *(float4*)(op + 4) = o1;
    }
  }
}

// ---------------- depthwise 3x3 + silu, writes row-major and transposed ----------------
__global__ __launch_bounds__(256) void k_dwconv(const float* __restrict__ xin, const float* __restrict__ dwW,
                                                float* __restrict__ out, float* __restrict__ outT){
  int bd = blockIdx.x;           // b*96+d
  int d = bd % 96;
  const float* ip = xin + (size_t)bd*Lpx;
  __shared__ float pl[Lpx];
  __shared__ float po[Lpx + 56];
  int tid = threadIdx.x;
  for (int i = tid; i < Lpx; i += 256) pl[i] = ip[i];
  float w9[9];
  #pragma unroll
  for (int t = 0; t < 9; ++t) w9[t] = dwW[d*9 + t];
  __syncthreads();
  for (int i = tid; i < Lpx; i += 256){
    int h = i / 56, w = i % 56;
    float s = 0.f;
    #pragma unroll
    for (int tap = 0; tap < 9; ++tap){
      int hh = h + tap/3 - 1, ww = w + tap%3 - 1;
      if (hh >= 0 && hh < 56 && ww >= 0 && ww < 56) s = fmaf(pl[hh*56 + ww], w9[tap], s);
    }
    po[i + i/56] = siluf_(s);
  }
  __syncthreads();
  float* op  = out  + (size_t)bd*Lpx;
  float* otp = outT + (size_t)bd*Lpx;
  for (int i = tid; i < Lpx; i += 256){
    op[i] = po[i + i/56];
    int q = (i % 56)*56 + i/56;
    otp[i] = po[q + q/56];        // stride-57 LDS read: conflict-free
  }
}

// ---------------- per-pixel 96->(4k x 8r) projections, row-major and transposed ----------------
__global__ __launch_bounds__(256) void k_proj(const float* __restrict__ xss, const float* __restrict__ xpw,
                                              float* __restrict__ PROJ, float* __restrict__ PROJT){
  int b = blockIdx.x / 56, h = blockIdx.x % 56;
  __shared__ float lx[96*56];    // [d][w]
  __shared__ float lw[32*96];    // [kr][d]
  int tid = threadIdx.x;
  const float* xb = xss + (size_t)b*CHW + h*56;
  for (int i = tid; i < 96*56; i += 256){
    int d = i / 56, w = i % 56;
    lx[i] = xb[(size_t)d*Lpx + w];
  }
  for (int i = tid; i < 32*96; i += 256) lw[i] = xpw[i];
  __syncthreads();
  for (int o = tid; o < 32*56; o += 256){
    int w = o % 56, kr = o / 56;
    float s = 0.f;
    for (int d = 0; d < 96; ++d) s = fmaf(lx[d*56 + w], lw[kr*96 + d], s);
    size_t base = ((size_t)b*32 + kr)*Lpx;
    PROJ[base + h*56 + w] = s;
    PROJT[base + w*56 + h] = s;
  }
}

// ---------------- block-parallel bidirectional selective scan ----------------
__global__ __launch_bounds__(256) void k_scan2(const float* __restrict__ x_rm, const float* __restrict__ x_cm,
                                               const float* __restrict__ PROJ, const float* __restrict__ PROJT,
                                               const float* __restrict__ dtw_all, const float* __restrict__ dtb_all,
                                               const float* __restrict__ Alog, const float* __restrict__ Dall,
                                               float* __restrict__ out0, float* __restrict__ out1){
  int bd = blockIdx.x; int b = bd / 96, d = bd % 96;
  int klo = blockIdx.y;
  const float* xv = (klo == 0 ? x_rm : x_cm) + (size_t)bd*Lpx;
  const float* PR = (klo == 0 ? PROJ : PROJT);
  float* yo = (klo == 0 ? out0 : out1) + (size_t)bd*Lpx;
  int kA = klo, kB = klo + 2;

  float dwA[6], dwB[6];
  #pragma unroll
  for (int r = 0; r < 6; ++r){ dwA[r] = dtw_all[(kA*96 + d)*6 + r]; dwB[r] = dtw_all[(kB*96 + d)*6 + r]; }
  float biA = dtb_all[kA*96 + d], biB = dtb_all[kB*96 + d];
  float AA = -expf(Alog[kA*96 + d]), AB = -expf(Alog[kB*96 + d]);
  float Dsum = Dall[kA*96 + d] + Dall[kB*96 + d];
  const float* pA = PR + ((size_t)b*32 + kA*8)*Lpx;
  const float* pB = PR + ((size_t)b*32 + kB*8)*Lpx;

  __shared__ float xb[Lpx];
  __shared__ float u[NPAD];
  __shared__ float v[NPAD];
  __shared__ float yacc[Lpx + 56];
  __shared__ float wag[8];

  int tid = threadIdx.x;
  int lane = tid & 63, wv = tid >> 6;
  int base = tid * 13;

  for (int i = tid; i < Lpx; i += 256) xb[i] = xv[i];

  // ======== direction A (forward in p) ========
  for (int i = tid; i < Lpx; i += 256){
    float z = biA;
    #pragma unroll
    for (int r = 0; r < 6; ++r) z = fmaf(dwA[r], pA[(size_t)r*Lpx + i], z);
    float dt = softplusf_(z);
    u[i] = expf(dt * AA);
    v[i] = dt * pA[(size_t)6*Lpx + i] * xb[i];
  }
  for (int i = Lpx + tid; i < NPAD; i += 256){ u[i] = 1.f; v[i] = 0.f; }
  __syncthreads();

  {
    float a = 1.f, bb = 0.f;
    #pragma unroll
    for (int j = 0; j < 13; ++j){
      float da = u[base + j], db = v[base + j];
      bb = fmaf(da, bb, db);
      a *= da;
      u[base + j] = a; v[base + j] = bb;
    }
    float aT = a, bT = bb;
    #pragma unroll
    for (int off = 1; off < 64; off <<= 1){
      float ap = __shfl_up(aT, off), bp = __shfl_up(bT, off);
      if (lane >= off){ bT = fmaf(aT, bp, bT); aT *= ap; }
    }
    if (lane == 63){ wag[wv] = aT; wag[4 + wv] = bT; }
    float a_ex = __shfl_up(aT, 1), b_ex = __shfl_up(bT, 1);
    if (lane == 0){ a_ex = 1.f; b_ex = 0.f; }
    __syncthreads();
    float hw = 0.f;
    for (int j = 0; j < wv; ++j) hw = fmaf(wag[j], hw, wag[4 + j]);
    float hin = fmaf(a_ex, hw, b_ex);
    #pragma unroll
    for (int j = 0; j < 13; ++j)
      v[base + j] = fmaf(u[base + j], hin, v[base + j]);
  }
  __syncthreads();
  for (int i = tid; i < Lpx; i += 256){
    float C = pA[(size_t)7*Lpx + i];
    yacc[i + i/56] = fmaf(C, v[i], Dsum * xb[i]);
  }
  __syncthreads();

  // ======== direction B (reverse in p) ========
  for (int i = tid; i < Lpx; i += 256){
    float z = biB;
    #pragma unroll
    for (int r = 0; r < 6; ++r) z = fmaf(dwB[r], pB[(size_t)r*Lpx + i], z);
    float dt = softplusf_(z);
    u[i] = expf(dt * AB);
    v[i] = dt * pB[(size_t)6*Lpx + i] * xb[i];
  }
  for (int i = Lpx + tid; i < NPAD; i += 256){ u[i] = 1.f; v[i] = 0.f; }
  __syncthreads();

  {
    float a = 1.f, bb = 0.f;
    #pragma unroll
    for (int j = 12; j >= 0; --j){
      float da = u[base + j], db = v[base + j];
      bb = fmaf(da, bb, db);
      a *= da;
      u[base + j] = a; v[base + j] = bb;
    }
    float aT = a, bT = bb;
    #pragma unroll
    for (int off = 1; off < 64; off <<= 1){
      float ap = __shfl_down(aT, off), bp = __shfl_down(bT, off);
      if (lane + off < 64){ bT = fmaf(aT, bp, bT); aT *= ap; }
    }
    if (lane == 0){ wag[wv] = aT; wag[4 + wv] = bT; }
    float a_ex = __shfl_down(aT, 1), b_ex = __shfl_down(bT, 1);
    if (lane == 63){ a_ex = 1.f; b_ex = 0.f; }
    __syncthreads();
    float hw = 0.f;
    for (int j = 3; j > wv; --j) hw = fmaf(wag[j], hw, wag[4 + j]);
    float hin = fmaf(a_ex, hw, b_ex);
    #pragma unroll
    for (int j = 0; j < 13; ++j)
      v[base + j] = fmaf(u[base + j], hin, v[base + j]);
  }
  __syncthreads();
  for (int i = tid; i < Lpx; i += 256){
    float C = pB[(size_t)7*Lpx + i];
    yacc[i + i/56] = fmaf(C, v[i], yacc[i + i/56]);
  }
  __syncthreads();

  if (klo == 0){
    for (int i = tid; i < Lpx; i += 256)
      yo[i] = yacc[i + i/56];
  } else {
    for (int i = tid; i < Lpx; i += 256){
      int q = (i % 56)*56 + i/56;
      yo[i] = yacc[q + q/56];
    }
  }
}

// ---------------- combine ya+yb, LayerNorm over channels (float4) ----------------
__global__ __launch_bounds__(256) void k_ln(const float* __restrict__ ya, const float* __restrict__ yb,
                                            const float* __restrict__ g, const float* __restrict__ be,
                                            float* __restrict__ out){
  int i4 = blockIdx.x*256 + threadIdx.x;    // < 16*784
  int b = i4 / 784, p = (i4 % 784) * 4;
  const float* ap = ya + (size_t)b*CHW + p;
  const float* bp = yb + (size_t)b*CHW + p;
  float4 s = {0.f,0.f,0.f,0.f};
  for (int d = 0; d < 96; ++d){
    float4 av = *(const float4*)&ap[(size_t)d*Lpx];
    float4 bv = *(const float4*)&bp[(size_t)d*Lpx];
    s.x += av.x + bv.x; s.y += av.y + bv.y; s.z += av.z + bv.z; s.w += av.w + bv.w;
  }
  float4 mu; mu.x = s.x*(1.f/96.f); mu.y = s.y*(1.f/96.f); mu.z = s.z*(1.f/96.f); mu.w = s.w*(1.f/96.f);
  float4 ss = {0.f,0.f,0.f,0.f};
  for (int d = 0; d < 96; ++d){
    float4 av = *(const float4*)&ap[(size_t)d*Lpx];
    float4 bv = *(const float4*)&bp[(size_t)d*Lpx];
    float vx = av.x + bv.x - mu.x, vy = av.y + bv.y - mu.y;
    float vz = av.z + bv.z - mu.z, vw = av.w + bv.w - mu.w;
    ss.x = fmaf(vx,vx,ss.x); ss.y = fmaf(vy,vy,ss.y); ss.z = fmaf(vz,vz,ss.z); ss.w = fmaf(vw,vw,ss.w);
  }
  float4 rs;
  rs.x = 1.f/sqrtf(ss.x*(1.f/96.f) + 1e-5f); rs.y = 1.f/sqrtf(ss.y*(1.f/96.f) + 1e-5f);
  rs.z = 1.f/sqrtf(ss.z*(1.f/96.f) + 1e-5f); rs.w = 1.f/sqrtf(ss.w*(1.f/96.f) + 1e-5f);
  float* op = out + (size_t)b*CHW + p;
  for (int d = 0; d < 96; ++d){
    float4 av = *(const float4*)&ap[(size_t)d*Lpx];
    float4 bv = *(const float4*)&bp[(size_t)d*Lpx];
    float gd = g[d], bd = be[d];
    float4 o;
    o.x = (av.x + bv.x - mu.x)*rs.x*gd + bd;
    o.y = (av.y + bv.y - mu.y)*rs.y*gd + bd;
    o.z = (av.z + bv.z - mu.z)*rs.z*gd + bd;
    o.w = (av.w + bv.w - mu.w)*rs.w*gd + bd;
    *(float4*)&op[(size_t)d*Lpx] = o;
  }
}

// ---------------- LIF over T=4 + multiply with original x (float4) ----------------
__global__ __launch_bounds__(256) void k_lif2(const float* __restrict__ yo, const float* __restrict__ x0,
                                              float* __restrict__ out){
  const int stride4 = 301056;   // B*C*L/4
  int i4 = blockIdx.x*256 + threadIdx.x;
  float4 v = {0.f,0.f,0.f,0.f};
  #pragma unroll
  for (int t = 0; t < 4; ++t){
    float4 z = *(const float4*)&yo[((size_t)t*stride4 + i4)*4];
    float4 xv = *(const float4*)&x0[((size_t)t*stride4 + i4)*4];
    v.x = 0.5f*(v.x + z.x); v.y = 0.5f*(v.y + z.y);
    v.z = 0.5f*(v.z + z.z); v.w = 0.5f*(v.w + z.w);
    float4 o;
    o.x = (v.x >= 1.0f) ? xv.x : 0.f; o.y = (v.y >= 1.0f) ? xv.y : 0.f;
    o.z = (v.z >= 1.0f) ? xv.z : 0.f; o.w = (v.w >= 1.0f) ? xv.w : 0.f;
    v.x = (v.x >= 1.0f) ? 0.f : v.x; v.y = (v.y >= 1.0f) ? 0.f : v.y;
    v.z = (v.z >= 1.0f) ? 0.f : v.z; v.w = (v.w >= 1.0f) ? 0.f : v.w;
    *(float4*)&out[((size_t)t*stride4 + i4)*4] = o;
  }
}

extern "C" void kernel_launch(void* const* d_in, const int* in_sizes, int n_in,
                              void* d_out, int out_size, void* d_ws, size_t ws_size,
                              hipStream_t stream) {
  const float* x    = (const float*)d_in[0];
  const float* ipw  = (const float*)d_in[1];
  const float* ipb  = (const float*)d_in[2];
  const float* cw   = (const float*)d_in[3];
  const float* cb   = (const float*)d_in[4];
  const float* siw  = (const float*)d_in[5];
  const float* scw  = (const float*)d_in[6];
  const float* xpw  = (const float*)d_in[7];
  const float* dtw  = (const float*)d_in[8];
  const float* dtb  = (const float*)d_in[9];
  const float* alog = (const float*)d_in[10];
  const float* dsv  = (const float*)d_in[11];
  const float* lng  = (const float*)d_in[12];
  const float* lnb  = (const float*)d_in[13];
  const float* opw  = (const float*)d_in[14];

  float* s1 = (float*)d_ws;
  float* s2 = s1 + SZn;
  float* s3 = s2 + SZn;
  float* s4 = s3 + SZn;
  float* pr  = s4 + SZn;
  float* prT = pr + PRJ;

  // 1) in_proj -> xp in s1
  k_matmul<<<784, 256, 0, stream>>>(x, ipw, ipb, s1);
  // 2) LIF over 16 steps -> uchar spikes in s2
  k_lif1<<<294, 256, 0, stream>>>(s1, (unsigned char*)s2);
  // 3) dense 3x3 conv, K-split partials -> s1 (ks0), s3 (ks1)
  k_conv6<<<dim3(16, 12, 7), 256, 0, stream>>>((const unsigned char*)s2, cw, s1, s3);
  // 4) merge(bias+silu) + ssm_in matmul -> s2
  k_matmulM<<<784, 256, 0, stream>>>(s1, s3, cb, siw, s2);
  // 5) depthwise conv + silu -> xss rm in s1, cm in s3
  k_dwconv<<<1536, 256, 0, stream>>>(s2, scw, s1, s3);
  // 6) projections (pixel-indexed, both layouts)
  k_proj<<<896, 256, 0, stream>>>(s1, xpw, pr, prT);
  // 7) both scan dir-pairs: ya -> s2, yb(row-major) -> s4
  k_scan2<<<dim3(1536, 2), 256, 0, stream>>>(s1, s3, pr, prT, dtw, dtb, alog, dsv, s2, s4);
  // 8) combine + LayerNorm -> s3
  k_ln<<<49, 256, 0, stream>>>(s2, s4, lng, lnb, s3);
  // 9) out_proj -> s2
  k_matmul<<<784, 256, 0, stream>>>(s3, opw, nullptr, s2);
  // 10) LIF over T=4, multiply with x -> d_out
  k_lif2<<<1176, 256, 0, stream>>>(s2, x, (float*)d_out);
}

// Round 12
// 505.693 us; speedup vs baseline: 1.9701x; 1.1466x over previous
//
#include <hip/hip_runtime.h>
#include <math.h>

#define TBn 16
#define Lpx 3136
#define CHW 301056      // 96*3136
#define SZn 4816896     // 16*96*3136
#define PRJ 1605632     // 16*32*3136
#define NPAD 3328       // 256*13

__device__ __forceinline__ float siluf_(float z){ return z / (1.f + expf(-z)); }

// ---------------- per-pixel channel matmul v2: full weight tile, ci unrolled x4 ----------------
__global__ __launch_bounds__(256) void k_matmul(const float* __restrict__ in, const float* __restrict__ Wm,
                                                const float* __restrict__ bias, float* __restrict__ out){
  int blk = blockIdx.x;
  int n = blk / 49, pt = blk % 49, p0 = pt * 64;
  __shared__ float lx[96*64];     // [ci][px]
  __shared__ float wl[96*100];    // [co][ci], stride 100
  int tid = threadIdx.x;
  const float* inb = in + (size_t)n*CHW;
  for (int i = tid; i < 96*64; i += 256){
    int ci = i >> 6, px = i & 63;
    lx[i] = inb[(size_t)ci*Lpx + p0 + px];
  }
  for (int i = tid; i < 96*96; i += 256){
    int co = i / 96, ci = i % 96;
    wl[co*100 + ci] = Wm[i];
  }
  int px_t = tid & 15, co_t = tid >> 4;
  float acc[6][4];
  #pragma unroll
  for (int j = 0; j < 6; ++j){
    float b = bias ? bias[co_t*6 + j] : 0.f;
    #pragma unroll
    for (int q = 0; q < 4; ++q) acc[j][q] = b;
  }
  __syncthreads();
  for (int c4 = 0; c4 < 24; ++c4){
    float4 xv0 = *(const float4*)&lx[(c4*4 + 0)*64 + px_t*4];
    float4 xv1 = *(const float4*)&lx[(c4*4 + 1)*64 + px_t*4];
    float4 xv2 = *(const float4*)&lx[(c4*4 + 2)*64 + px_t*4];
    float4 xv3 = *(const float4*)&lx[(c4*4 + 3)*64 + px_t*4];
    #pragma unroll
    for (int j = 0; j < 6; ++j){
      float4 wv = *(const float4*)&wl[(co_t*6 + j)*100 + c4*4];
      acc[j][0] = fmaf(wv.x, xv0.x, acc[j][0]); acc[j][1] = fmaf(wv.x, xv0.y, acc[j][1]);
      acc[j][2] = fmaf(wv.x, xv0.z, acc[j][2]); acc[j][3] = fmaf(wv.x, xv0.w, acc[j][3]);
      acc[j][0] = fmaf(wv.y, xv1.x, acc[j][0]); acc[j][1] = fmaf(wv.y, xv1.y, acc[j][1]);
      acc[j][2] = fmaf(wv.y, xv1.z, acc[j][2]); acc[j][3] = fmaf(wv.y, xv1.w, acc[j][3]);
      acc[j][0] = fmaf(wv.z, xv2.x, acc[j][0]); acc[j][1] = fmaf(wv.z, xv2.y, acc[j][1]);
      acc[j][2] = fmaf(wv.z, xv2.z, acc[j][2]); acc[j][3] = fmaf(wv.z, xv2.w, acc[j][3]);
      acc[j][0] = fmaf(wv.w, xv3.x, acc[j][0]); acc[j][1] = fmaf(wv.w, xv3.y, acc[j][1]);
      acc[j][2] = fmaf(wv.w, xv3.z, acc[j][2]); acc[j][3] = fmaf(wv.w, xv3.w, acc[j][3]);
    }
  }
  float* ob = out + (size_t)n*CHW + p0 + px_t*4;
  #pragma unroll
  for (int j = 0; j < 6; ++j){
    float4 v; v.x = acc[j][0]; v.y = acc[j][1]; v.z = acc[j][2]; v.w = acc[j][3];
    *(float4*)&ob[(size_t)(co_t*6 + j)*Lpx] = v;
  }
}

// ---------------- matmul merge variant: in = silu(pA+pB+cb), no matmul bias ----------------
__global__ __launch_bounds__(256) void k_matmulM(const float* __restrict__ pA, const float* __restrict__ pB,
                                                 const float* __restrict__ cbias, const float* __restrict__ Wm,
                                                 float* __restrict__ out){
  int blk = blockIdx.x;
  int n = blk / 49, pt = blk % 49, p0 = pt * 64;
  __shared__ float lx[96*64];
  __shared__ float wl[96*100];
  int tid = threadIdx.x;
  const float* inA = pA + (size_t)n*CHW;
  const float* inB = pB + (size_t)n*CHW;
  for (int i = tid; i < 96*64; i += 256){
    int ci = i >> 6, px = i & 63;
    float z = inA[(size_t)ci*Lpx + p0 + px] + inB[(size_t)ci*Lpx + p0 + px] + cbias[ci];
    lx[i] = siluf_(z);
  }
  for (int i = tid; i < 96*96; i += 256){
    int co = i / 96, ci = i % 96;
    wl[co*100 + ci] = Wm[i];
  }
  int px_t = tid & 15, co_t = tid >> 4;
  float acc[6][4];
  #pragma unroll
  for (int j = 0; j < 6; ++j)
    #pragma unroll
    for (int q = 0; q < 4; ++q) acc[j][q] = 0.f;
  __syncthreads();
  for (int c4 = 0; c4 < 24; ++c4){
    float4 xv0 = *(const float4*)&lx[(c4*4 + 0)*64 + px_t*4];
    float4 xv1 = *(const float4*)&lx[(c4*4 + 1)*64 + px_t*4];
    float4 xv2 = *(const float4*)&lx[(c4*4 + 2)*64 + px_t*4];
    float4 xv3 = *(const float4*)&lx[(c4*4 + 3)*64 + px_t*4];
    #pragma unroll
    for (int j = 0; j < 6; ++j){
      float4 wv = *(const float4*)&wl[(co_t*6 + j)*100 + c4*4];
      acc[j][0] = fmaf(wv.x, xv0.x, acc[j][0]); acc[j][1] = fmaf(wv.x, xv0.y, acc[j][1]);
      acc[j][2] = fmaf(wv.x, xv0.z, acc[j][2]); acc[j][3] = fmaf(wv.x, xv0.w, acc[j][3]);
      acc[j][0] = fmaf(wv.y, xv1.x, acc[j][0]); acc[j][1] = fmaf(wv.y, xv1.y, acc[j][1]);
      acc[j][2] = fmaf(wv.y, xv1.z, acc[j][2]); acc[j][3] = fmaf(wv.y, xv1.w, acc[j][3]);
      acc[j][0] = fmaf(wv.z, xv2.x, acc[j][0]); acc[j][1] = fmaf(wv.z, xv2.y, acc[j][1]);
      acc[j][2] = fmaf(wv.z, xv2.z, acc[j][2]); acc[j][3] = fmaf(wv.z, xv2.w, acc[j][3]);
      acc[j][0] = fmaf(wv.w, xv3.x, acc[j][0]); acc[j][1] = fmaf(wv.w, xv3.y, acc[j][1]);
      acc[j][2] = fmaf(wv.w, xv3.z, acc[j][2]); acc[j][3] = fmaf(wv.w, xv3.w, acc[j][3]);
    }
  }
  float* ob = out + (size_t)n*CHW + p0 + px_t*4;
  #pragma unroll
  for (int j = 0; j < 6; ++j){
    float4 v; v.x = acc[j][0]; v.y = acc[j][1]; v.z = acc[j][2]; v.w = acc[j][3];
    *(float4*)&ob[(size_t)(co_t*6 + j)*Lpx] = v;
  }
}

// ---------------- LIF over 16 steps, float4, uchar spike output ----------------
__global__ __launch_bounds__(256) void k_lif1(const float* __restrict__ xp, unsigned char* __restrict__ sp){
  int i4 = blockIdx.x*256 + threadIdx.x;     // < CHW/4
  float4 v = {0.f,0.f,0.f,0.f};
  #pragma unroll
  for (int t = 0; t < 16; ++t){
    float4 z = *(const float4*)&xp[(size_t)t*CHW + (size_t)i4*4];
    v.x = 0.5f*(v.x + z.x); v.y = 0.5f*(v.y + z.y);
    v.z = 0.5f*(v.z + z.z); v.w = 0.5f*(v.w + z.w);
    uchar4 s;
    s.x = (v.x >= 1.0f); s.y = (v.y >= 1.0f); s.z = (v.z >= 1.0f); s.w = (v.w >= 1.0f);
    *(uchar4*)&sp[(size_t)t*CHW + (size_t)i4*4] = s;
    v.x = s.x ? 0.f : v.x; v.y = s.y ? 0.f : v.y;
    v.z = s.z ? 0.f : v.z; v.w = s.w ? 0.f : v.w;
  }
}

// ---------------- dense 3x3 conv v6: SGPR weights (wave-uniform co-quad) + K-split ----------------
#define CIC3 8
__global__ __launch_bounds__(256) void k_conv6(const unsigned char* __restrict__ spk, const float* __restrict__ cw,
                                               float* __restrict__ outP0, float* __restrict__ outP1){
  int b = blockIdx.x;
  int cog = blockIdx.y % 6, ks = blockIdx.y / 6;
  int hb = blockIdx.z;
  int co0 = cog*16, h0 = hb*8;
  int tid = threadIdx.x;
  int wid = tid >> 6, lane = tid & 63;
  int hl = lane >> 3, wq = lane & 7;         // wq<7 active
  int coq = __builtin_amdgcn_readfirstlane(wid);
  __shared__ float xl[CIC3*10*68];           // [ci][row 0..9][col, stride 68]
  float acc[4][8];
  #pragma unroll
  for (int j = 0; j < 4; ++j)
    #pragma unroll
    for (int q = 0; q < 8; ++q) acc[j][q] = 0.f;

  for (int cc = ks*6; cc < ks*6 + 6; ++cc){
    __syncthreads();
    for (int i = tid; i < CIC3*10*58; i += 256){
      int ci = i / 580, rem = i % 580;
      int hh = rem / 58, ww = rem % 58;
      int sh = h0 - 1 + hh, sw = ww - 1;
      float v = 0.f;
      if (sh >= 0 && sh < 56 && sw >= 0 && sw < 56)
        v = (float)spk[(((size_t)b*96 + cc*CIC3 + ci)*56 + sh)*56 + sw];
      xl[ci*680 + hh*68 + ww] = v;
    }
    __syncthreads();
    for (int ci = 0; ci < CIC3; ++ci){
      int cig = cc*CIC3 + ci;
      float wj[9][4];
      #pragma unroll
      for (int tap = 0; tap < 9; ++tap)
        #pragma unroll
        for (int j = 0; j < 4; ++j)
          wj[tap][j] = cw[(((size_t)(co0 + coq*4 + j))*96 + cig)*9 + tap];
      float xr[3][10];
      int base = ci*680 + hl*68 + wq*8;
      #pragma unroll
      for (int dh = 0; dh < 3; ++dh){
        float4 a = *(const float4*)&xl[base + dh*68];
        float4 c = *(const float4*)&xl[base + dh*68 + 4];
        float2 e = *(const float2*)&xl[base + dh*68 + 8];
        xr[dh][0] = a.x; xr[dh][1] = a.y; xr[dh][2] = a.z; xr[dh][3] = a.w;
        xr[dh][4] = c.x; xr[dh][5] = c.y; xr[dh][6] = c.z; xr[dh][7] = c.w;
        xr[dh][8] = e.x; xr[dh][9] = e.y;
      }
      #pragma unroll
      for (int tap = 0; tap < 9; ++tap){
        const int dh = tap/3, dw = tap%3;
        #pragma unroll
        for (int q = 0; q < 8; ++q){
          float xv = xr[dh][q + dw];
          acc[0][q] = fmaf(xv, wj[tap][0], acc[0][q]);
          acc[1][q] = fmaf(xv, wj[tap][1], acc[1][q]);
          acc[2][q] = fmaf(xv, wj[tap][2], acc[2][q]);
          acc[3][q] = fmaf(xv, wj[tap][3], acc[3][q]);
        }
      }
    }
  }
  if (wq < 7){
    float* outp = (ks == 0) ? outP0 : outP1;
    #pragma unroll
    for (int j = 0; j < 4; ++j){
      int co = co0 + coq*4 + j;
      float4 o0, o1;
      o0.x = acc[j][0]; o0.y = acc[j][1]; o0.z = acc[j][2]; o0.w = acc[j][3];
      o1.x = acc[j][4]; o1.y = acc[j][5]; o1.z = acc[j][6]; o1.w = acc[j][7];
      float* op = &outp[(((size_t)b*96 + co)*56 + h0 + hl)*56 + wq*8];
      *(float4*)op = o0;
      *(float4*)(op + 4) = o1;
    }
  }
}

// ---------------- depthwise 3x3 + silu, writes row-major and transposed ----------------
__global__ __launch_bounds__(256) void k_dwconv(const float* __restrict__ xin, const float* __restrict__ dwW,
                                                float* __restrict__ out, float* __restrict__ outT){
  int bd = blockIdx.x;           // b*96+d
  int d = bd % 96;
  const float* ip = xin + (size_t)bd*Lpx;
  __shared__ float pl[Lpx];
  __shared__ float po[Lpx + 56];
  int tid = threadIdx.x;
  for (int i = tid; i < Lpx; i += 256) pl[i] = ip[i];
  float w9[9];
  #pragma unroll
  for (int t = 0; t < 9; ++t) w9[t] = dwW[d*9 + t];
  __syncthreads();
  for (int i = tid; i < Lpx; i += 256){
    int h = i / 56, w = i % 56;
    float s = 0.f;
    #pragma unroll
    for (int tap = 0; tap < 9; ++tap){
      int hh = h + tap/3 - 1, ww = w + tap%3 - 1;
      if (hh >= 0 && hh < 56 && ww >= 0 && ww < 56) s = fmaf(pl[hh*56 + ww], w9[tap], s);
    }
    po[i + i/56] = siluf_(s);
  }
  __syncthreads();
  float* op  = out  + (size_t)bd*Lpx;
  float* otp = outT + (size_t)bd*Lpx;
  for (int i = tid; i < Lpx; i += 256){
    op[i] = po[i + i/56];
    int q = (i % 56)*56 + i/56;
    otp[i] = po[q + q/56];        // stride-57 LDS read: conflict-free
  }
}

// ---------------- per-pixel 96->(4k x 8r) projections, row-major and transposed ----------------
__global__ __launch_bounds__(256) void k_proj(const float* __restrict__ xss, const float* __restrict__ xpw,
                                              float* __restrict__ PROJ, float* __restrict__ PROJT){
  int b = blockIdx.x / 56, h = blockIdx.x % 56;
  __shared__ float lx[96*56];    // [d][w]
  __shared__ float lw[32*96];    // [kr][d]
  int tid = threadIdx.x;
  const float* xb = xss + (size_t)b*CHW + h*56;
  for (int i = tid; i < 96*56; i += 256){
    int d = i / 56, w = i % 56;
    lx[i] = xb[(size_t)d*Lpx + w];
  }
  for (int i = tid; i < 32*96; i += 256) lw[i] = xpw[i];
  __syncthreads();
  for (int o = tid; o < 32*56; o += 256){
    int w = o % 56, kr = o / 56;
    float s = 0.f;
    for (int d = 0; d < 96; ++d) s = fmaf(lx[d*56 + w], lw[kr*96 + d], s);
    size_t base = ((size_t)b*32 + kr)*Lpx;
    PROJ[base + h*56 + w] = s;
    PROJT[base + w*56 + h] = s;
  }
}

// ---------------- block-parallel bidirectional selective scan v3 ----------------
// exp2/log2-domain transcendentals; no xb buffer (x re-read, L2-hot); register local scans.
__global__ __launch_bounds__(256) void k_scan3(const float* __restrict__ x_rm, const float* __restrict__ x_cm,
                                               const float* __restrict__ PROJ, const float* __restrict__ PROJT,
                                               const float* __restrict__ dtw_all, const float* __restrict__ dtb_all,
                                               const float* __restrict__ Alog, const float* __restrict__ Dall,
                                               float* __restrict__ out0, float* __restrict__ out1){
  int bd = blockIdx.x; int b = bd / 96, d = bd % 96;
  int klo = blockIdx.y;
  const float* xv = (klo == 0 ? x_rm : x_cm) + (size_t)bd*Lpx;
  const float* PR = (klo == 0 ? PROJ : PROJT);
  float* yo = (klo == 0 ? out0 : out1) + (size_t)bd*Lpx;
  int kA = klo, kB = klo + 2;
  const float L2E = 1.44269504f, LN2 = 0.69314718f;

  float dwA[6], dwB[6];
  #pragma unroll
  for (int r = 0; r < 6; ++r){ dwA[r] = dtw_all[(kA*96 + d)*6 + r]; dwB[r] = dtw_all[(kB*96 + d)*6 + r]; }
  float biA = dtb_all[kA*96 + d], biB = dtb_all[kB*96 + d];
  float AA = -expf(Alog[kA*96 + d]) * L2E;   // pre-scaled: exp(dt*A) = exp2(dt*AA)
  float AB = -expf(Alog[kB*96 + d]) * L2E;
  float Dsum = Dall[kA*96 + d] + Dall[kB*96 + d];
  const float* pA = PR + ((size_t)b*32 + kA*8)*Lpx;
  const float* pB = PR + ((size_t)b*32 + kB*8)*Lpx;

  __shared__ float u[NPAD];
  __shared__ float v[NPAD];
  __shared__ float yacc[Lpx + 56];
  __shared__ float wag[8];

  int tid = threadIdx.x;
  int lane = tid & 63, wv = tid >> 6;
  int base = tid * 13;
  float la[13], lb[13];

  // ======== direction A (forward in p) ========
  for (int i = tid; i < Lpx; i += 256){
    float z = biA;
    #pragma unroll
    for (int r = 0; r < 6; ++r) z = fmaf(dwA[r], pA[(size_t)r*Lpx + i], z);
    float t = exp2f(-fabsf(z) * L2E);
    float dt = fmaxf(z, 0.f) + LN2 * log2f(1.f + t);
    u[i] = exp2f(dt * AA);
    v[i] = dt * pA[(size_t)6*Lpx + i] * xv[i];
  }
  for (int i = Lpx + tid; i < NPAD; i += 256){ u[i] = 1.f; v[i] = 0.f; }
  __syncthreads();

  {
    float a = 1.f, bb = 0.f;
    #pragma unroll
    for (int j = 0; j < 13; ++j){
      float da = u[base + j], db = v[base + j];
      bb = fmaf(da, bb, db);
      a *= da;
      la[j] = a; lb[j] = bb;
    }
    float aT = a, bT = bb;
    #pragma unroll
    for (int off = 1; off < 64; off <<= 1){
      float ap = __shfl_up(aT, off), bp = __shfl_up(bT, off);
      if (lane >= off){ bT = fmaf(aT, bp, bT); aT *= ap; }
    }
    if (lane == 63){ wag[wv] = aT; wag[4 + wv] = bT; }
    float a_ex = __shfl_up(aT, 1), b_ex = __shfl_up(bT, 1);
    if (lane == 0){ a_ex = 1.f; b_ex = 0.f; }
    __syncthreads();
    float hw = 0.f;
    for (int j = 0; j < wv; ++j) hw = fmaf(wag[j], hw, wag[4 + j]);
    float hin = fmaf(a_ex, hw, b_ex);
    #pragma unroll
    for (int j = 0; j < 13; ++j)
      v[base + j] = fmaf(la[j], hin, lb[j]);
  }
  __syncthreads();
  for (int i = tid; i < Lpx; i += 256){
    float C = pA[(size_t)7*Lpx + i];
    yacc[i + i/56] = fmaf(C, v[i], Dsum * xv[i]);
  }
  __syncthreads();

  // ======== direction B (reverse in p) ========
  for (int i = tid; i < Lpx; i += 256){
    float z = biB;
    #pragma unroll
    for (int r = 0; r < 6; ++r) z = fmaf(dwB[r], pB[(size_t)r*Lpx + i], z);
    float t = exp2f(-fabsf(z) * L2E);
    float dt = fmaxf(z, 0.f) + LN2 * log2f(1.f + t);
    u[i] = exp2f(dt * AB);
    v[i] = dt * pB[(size_t)6*Lpx + i] * xv[i];
  }
  for (int i = Lpx + tid; i < NPAD; i += 256){ u[i] = 1.f; v[i] = 0.f; }
  __syncthreads();

  {
    float a = 1.f, bb = 0.f;
    #pragma unroll
    for (int j = 12; j >= 0; --j){
      float da = u[base + j], db = v[base + j];
      bb = fmaf(da, bb, db);
      a *= da;
      la[j] = a; lb[j] = bb;
    }
    float aT = a, bT = bb;
    #pragma unroll
    for (int off = 1; off < 64; off <<= 1){
      float ap = __shfl_down(aT, off), bp = __shfl_down(bT, off);
      if (lane + off < 64){ bT = fmaf(aT, bp, bT); aT *= ap; }
    }
    if (lane == 0){ wag[wv] = aT; wag[4 + wv] = bT; }
    float a_ex = __shfl_down(aT, 1), b_ex = __shfl_down(bT, 1);
    if (lane == 63){ a_ex = 1.f; b_ex = 0.f; }
    __syncthreads();
    float hw = 0.f;
    for (int j = 3; j > wv; --j) hw = fmaf(wag[j], hw, wag[4 + j]);
    float hin = fmaf(a_ex, hw, b_ex);
    #pragma unroll
    for (int j = 0; j < 13; ++j)
      v[base + j] = fmaf(la[j], hin, lb[j]);
  }
  __syncthreads();
  for (int i = tid; i < Lpx; i += 256){
    float C = pB[(size_t)7*Lpx + i];
    yacc[i + i/56] = fmaf(C, v[i], yacc[i + i/56]);
  }
  __syncthreads();

  if (klo == 0){
    for (int i = tid; i < Lpx; i += 256)
      yo[i] = yacc[i + i/56];
  } else {
    for (int i = tid; i < Lpx; i += 256){
      int q = (i % 56)*56 + i/56;
      yo[i] = yacc[q + q/56];
    }
  }
}

// ---------------- combine ya+yb, LayerNorm over channels (float4) ----------------
__global__ __launch_bounds__(256) void k_ln(const float* __restrict__ ya, const float* __restrict__ yb,
                                            const float* __restrict__ g, const float* __restrict__ be,
                                            float* __restrict__ out){
  int i4 = blockIdx.x*256 + threadIdx.x;    // < 16*784
  int b = i4 / 784, p = (i4 % 784) * 4;
  const float* ap = ya + (size_t)b*CHW + p;
  const float* bp = yb + (size_t)b*CHW + p;
  float4 s = {0.f,0.f,0.f,0.f};
  for (int d = 0; d < 96; ++d){
    float4 av = *(const float4*)&ap[(size_t)d*Lpx];
    float4 bv = *(const float4*)&bp[(size_t)d*Lpx];
    s.x += av.x + bv.x; s.y += av.y + bv.y; s.z += av.z + bv.z; s.w += av.w + bv.w;
  }
  float4 mu; mu.x = s.x*(1.f/96.f); mu.y = s.y*(1.f/96.f); mu.z = s.z*(1.f/96.f); mu.w = s.w*(1.f/96.f);
  float4 ss = {0.f,0.f,0.f,0.f};
  for (int d = 0; d < 96; ++d){
    float4 av = *(const float4*)&ap[(size_t)d*Lpx];
    float4 bv = *(const float4*)&bp[(size_t)d*Lpx];
    float vx = av.x + bv.x - mu.x, vy = av.y + bv.y - mu.y;
    float vz = av.z + bv.z - mu.z, vw = av.w + bv.w - mu.w;
    ss.x = fmaf(vx,vx,ss.x); ss.y = fmaf(vy,vy,ss.y); ss.z = fmaf(vz,vz,ss.z); ss.w = fmaf(vw,vw,ss.w);
  }
  float4 rs;
  rs.x = 1.f/sqrtf(ss.x*(1.f/96.f) + 1e-5f); rs.y = 1.f/sqrtf(ss.y*(1.f/96.f) + 1e-5f);
  rs.z = 1.f/sqrtf(ss.z*(1.f/96.f) + 1e-5f); rs.w = 1.f/sqrtf(ss.w*(1.f/96.f) + 1e-5f);
  float* op = out + (size_t)b*CHW + p;
  for (int d = 0; d < 96; ++d){
    float4 av = *(const float4*)&ap[(size_t)d*Lpx];
    float4 bv = *(const float4*)&bp[(size_t)d*Lpx];
    float gd = g[d], bd = be[d];
    float4 o;
    o.x = (av.x + bv.x - mu.x)*rs.x*gd + bd;
    o.y = (av.y + bv.y - mu.y)*rs.y*gd + bd;
    o.z = (av.z + bv.z - mu.z)*rs.z*gd + bd;
    o.w = (av.w + bv.w - mu.w)*rs.w*gd + bd;
    *(float4*)&op[(size_t)d*Lpx] = o;
  }
}

// ---------------- LIF over T=4 + multiply with original x (float4) ----------------
__global__ __launch_bounds__(256) void k_lif2(const float* __restrict__ yo, const float* __restrict__ x0,
                                              float* __restrict__ out){
  const int stride4 = 301056;   // B*C*L/4
  int i4 = blockIdx.x*256 + threadIdx.x;
  float4 v = {0.f,0.f,0.f,0.f};
  #pragma unroll
  for (int t = 0; t < 4; ++t){
    float4 z = *(const float4*)&yo[((size_t)t*stride4 + i4)*4];
    float4 xv = *(const float4*)&x0[((size_t)t*stride4 + i4)*4];
    v.x = 0.5f*(v.x + z.x); v.y = 0.5f*(v.y + z.y);
    v.z = 0.5f*(v.z + z.z); v.w = 0.5f*(v.w + z.w);
    float4 o;
    o.x = (v.x >= 1.0f) ? xv.x : 0.f; o.y = (v.y >= 1.0f) ? xv.y : 0.f;
    o.z = (v.z >= 1.0f) ? xv.z : 0.f; o.w = (v.w >= 1.0f) ? xv.w : 0.f;
    v.x = (v.x >= 1.0f) ? 0.f : v.x; v.y = (v.y >= 1.0f) ? 0.f : v.y;
    v.z = (v.z >= 1.0f) ? 0.f : v.z; v.w = (v.w >= 1.0f) ? 0.f : v.w;
    *(float4*)&out[((size_t)t*stride4 + i4)*4] = o;
  }
}

extern "C" void kernel_launch(void* const* d_in, const int* in_sizes, int n_in,
                              void* d_out, int out_size, void* d_ws, size_t ws_size,
                              hipStream_t stream) {
  const float* x    = (const float*)d_in[0];
  const float* ipw  = (const float*)d_in[1];
  const float* ipb  = (const float*)d_in[2];
  const float* cw   = (const float*)d_in[3];
  const float* cb   = (const float*)d_in[4];
  const float* siw  = (const float*)d_in[5];
  const float* scw  = (const float*)d_in[6];
  const float* xpw  = (const float*)d_in[7];
  const float* dtw  = (const float*)d_in[8];
  const float* dtb  = (const float*)d_in[9];
  const float* alog = (const float*)d_in[10];
  const float* dsv  = (const float*)d_in[11];
  const float* lng  = (const float*)d_in[12];
  const float* lnb  = (const float*)d_in[13];
  const float* opw  = (const float*)d_in[14];

  float* s1 = (float*)d_ws;
  float* s2 = s1 + SZn;
  float* s3 = s2 + SZn;
  float* s4 = s3 + SZn;
  float* pr  = s4 + SZn;
  float* prT = pr + PRJ;

  // 1) in_proj -> xp in s1
  k_matmul<<<784, 256, 0, stream>>>(x, ipw, ipb, s1);
  // 2) LIF over 16 steps -> uchar spikes in s2
  k_lif1<<<294, 256, 0, stream>>>(s1, (unsigned char*)s2);
  // 3) dense 3x3 conv, K-split partials -> s1 (ks0), s3 (ks1)
  k_conv6<<<dim3(16, 12, 7), 256, 0, stream>>>((const unsigned char*)s2, cw, s1, s3);
  // 4) merge(bias+silu) + ssm_in matmul -> s2
  k_matmulM<<<784, 256, 0, stream>>>(s1, s3, cb, siw, s2);
  // 5) depthwise conv + silu -> xss rm in s1, cm in s3
  k_dwconv<<<1536, 256, 0, stream>>>(s2, scw, s1, s3);
  // 6) projections (pixel-indexed, both layouts)
  k_proj<<<896, 256, 0, stream>>>(s1, xpw, pr, prT);
  // 7) both scan dir-pairs: ya -> s2, yb(row-major) -> s4
  k_scan3<<<dim3(1536, 2), 256, 0, stream>>>(s1, s3, pr, prT, dtw, dtb, alog, dsv, s2, s4);
  // 8) combine + LayerNorm -> s3
  k_ln<<<49, 256, 0, stream>>>(s2, s4, lng, lnb, s3);
  // 9) out_proj -> s2
  k_matmul<<<784, 256, 0, stream>>>(s3, opw, nullptr, s2);
  // 10) LIF over T=4, multiply with x -> d_out
  k_lif2<<<1176, 256, 0, stream>>>(s2, x, (float*)d_out);
}

// Round 13
// 475.940 us; speedup vs baseline: 2.0933x; 1.0625x over previous
//
#include <hip/hip_runtime.h>
#include <math.h>

#define TBn 16
#define Lpx 3136
#define CHW 301056      // 96*3136
#define SZn 4816896     // 16*96*3136
#define PRJ 1605632     // 16*32*3136
#define NPAD 3328       // 256*13

__device__ __forceinline__ float siluf_(float z){ return z / (1.f + expf(-z)); }

// ---------------- per-pixel channel matmul v2: full weight tile, ci unrolled x4 ----------------
__global__ __launch_bounds__(256) void k_matmul(const float* __restrict__ in, const float* __restrict__ Wm,
                                                const float* __restrict__ bias, float* __restrict__ out){
  int blk = blockIdx.x;
  int n = blk / 49, pt = blk % 49, p0 = pt * 64;
  __shared__ float lx[96*64];     // [ci][px]
  __shared__ float wl[96*100];    // [co][ci], stride 100
  int tid = threadIdx.x;
  const float* inb = in + (size_t)n*CHW;
  for (int i = tid; i < 96*64; i += 256){
    int ci = i >> 6, px = i & 63;
    lx[i] = inb[(size_t)ci*Lpx + p0 + px];
  }
  for (int i = tid; i < 96*96; i += 256){
    int co = i / 96, ci = i % 96;
    wl[co*100 + ci] = Wm[i];
  }
  int px_t = tid & 15, co_t = tid >> 4;
  float acc[6][4];
  #pragma unroll
  for (int j = 0; j < 6; ++j){
    float b = bias ? bias[co_t*6 + j] : 0.f;
    #pragma unroll
    for (int q = 0; q < 4; ++q) acc[j][q] = b;
  }
  __syncthreads();
  for (int c4 = 0; c4 < 24; ++c4){
    float4 xv0 = *(const float4*)&lx[(c4*4 + 0)*64 + px_t*4];
    float4 xv1 = *(const float4*)&lx[(c4*4 + 1)*64 + px_t*4];
    float4 xv2 = *(const float4*)&lx[(c4*4 + 2)*64 + px_t*4];
    float4 xv3 = *(const float4*)&lx[(c4*4 + 3)*64 + px_t*4];
    #pragma unroll
    for (int j = 0; j < 6; ++j){
      float4 wv = *(const float4*)&wl[(co_t*6 + j)*100 + c4*4];
      acc[j][0] = fmaf(wv.x, xv0.x, acc[j][0]); acc[j][1] = fmaf(wv.x, xv0.y, acc[j][1]);
      acc[j][2] = fmaf(wv.x, xv0.z, acc[j][2]); acc[j][3] = fmaf(wv.x, xv0.w, acc[j][3]);
      acc[j][0] = fmaf(wv.y, xv1.x, acc[j][0]); acc[j][1] = fmaf(wv.y, xv1.y, acc[j][1]);
      acc[j][2] = fmaf(wv.y, xv1.z, acc[j][2]); acc[j][3] = fmaf(wv.y, xv1.w, acc[j][3]);
      acc[j][0] = fmaf(wv.z, xv2.x, acc[j][0]); acc[j][1] = fmaf(wv.z, xv2.y, acc[j][1]);
      acc[j][2] = fmaf(wv.z, xv2.z, acc[j][2]); acc[j][3] = fmaf(wv.z, xv2.w, acc[j][3]);
      acc[j][0] = fmaf(wv.w, xv3.x, acc[j][0]); acc[j][1] = fmaf(wv.w, xv3.y, acc[j][1]);
      acc[j][2] = fmaf(wv.w, xv3.z, acc[j][2]); acc[j][3] = fmaf(wv.w, xv3.w, acc[j][3]);
    }
  }
  float* ob = out + (size_t)n*CHW + p0 + px_t*4;
  #pragma unroll
  for (int j = 0; j < 6; ++j){
    float4 v; v.x = acc[j][0]; v.y = acc[j][1]; v.z = acc[j][2]; v.w = acc[j][3];
    *(float4*)&ob[(size_t)(co_t*6 + j)*Lpx] = v;
  }
}

// ---------------- matmul merge variant: in = silu(pA+pB+pC+cb) ----------------
__global__ __launch_bounds__(256) void k_matmulM(const float* __restrict__ pA, const float* __restrict__ pB,
                                                 const float* __restrict__ pC, const float* __restrict__ cbias,
                                                 const float* __restrict__ Wm, float* __restrict__ out){
  int blk = blockIdx.x;
  int n = blk / 49, pt = blk % 49, p0 = pt * 64;
  __shared__ float lx[96*64];
  __shared__ float wl[96*100];
  int tid = threadIdx.x;
  const float* inA = pA + (size_t)n*CHW;
  const float* inB = pB + (size_t)n*CHW;
  const float* inC = pC + (size_t)n*CHW;
  for (int i = tid; i < 96*64; i += 256){
    int ci = i >> 6, px = i & 63;
    size_t off = (size_t)ci*Lpx + p0 + px;
    float z = inA[off] + inB[off] + inC[off] + cbias[ci];
    lx[i] = siluf_(z);
  }
  for (int i = tid; i < 96*96; i += 256){
    int co = i / 96, ci = i % 96;
    wl[co*100 + ci] = Wm[i];
  }
  int px_t = tid & 15, co_t = tid >> 4;
  float acc[6][4];
  #pragma unroll
  for (int j = 0; j < 6; ++j)
    #pragma unroll
    for (int q = 0; q < 4; ++q) acc[j][q] = 0.f;
  __syncthreads();
  for (int c4 = 0; c4 < 24; ++c4){
    float4 xv0 = *(const float4*)&lx[(c4*4 + 0)*64 + px_t*4];
    float4 xv1 = *(const float4*)&lx[(c4*4 + 1)*64 + px_t*4];
    float4 xv2 = *(const float4*)&lx[(c4*4 + 2)*64 + px_t*4];
    float4 xv3 = *(const float4*)&lx[(c4*4 + 3)*64 + px_t*4];
    #pragma unroll
    for (int j = 0; j < 6; ++j){
      float4 wv = *(const float4*)&wl[(co_t*6 + j)*100 + c4*4];
      acc[j][0] = fmaf(wv.x, xv0.x, acc[j][0]); acc[j][1] = fmaf(wv.x, xv0.y, acc[j][1]);
      acc[j][2] = fmaf(wv.x, xv0.z, acc[j][2]); acc[j][3] = fmaf(wv.x, xv0.w, acc[j][3]);
      acc[j][0] = fmaf(wv.y, xv1.x, acc[j][0]); acc[j][1] = fmaf(wv.y, xv1.y, acc[j][1]);
      acc[j][2] = fmaf(wv.y, xv1.z, acc[j][2]); acc[j][3] = fmaf(wv.y, xv1.w, acc[j][3]);
      acc[j][0] = fmaf(wv.z, xv2.x, acc[j][0]); acc[j][1] = fmaf(wv.z, xv2.y, acc[j][1]);
      acc[j][2] = fmaf(wv.z, xv2.z, acc[j][2]); acc[j][3] = fmaf(wv.z, xv2.w, acc[j][3]);
      acc[j][0] = fmaf(wv.w, xv3.x, acc[j][0]); acc[j][1] = fmaf(wv.w, xv3.y, acc[j][1]);
      acc[j][2] = fmaf(wv.w, xv3.z, acc[j][2]); acc[j][3] = fmaf(wv.w, xv3.w, acc[j][3]);
    }
  }
  float* ob = out + (size_t)n*CHW + p0 + px_t*4;
  #pragma unroll
  for (int j = 0; j < 6; ++j){
    float4 v; v.x = acc[j][0]; v.y = acc[j][1]; v.z = acc[j][2]; v.w = acc[j][3];
    *(float4*)&ob[(size_t)(co_t*6 + j)*Lpx] = v;
  }
}

// ---------------- LIF over 16 steps, float4, uchar spike output ----------------
__global__ __launch_bounds__(256) void k_lif1(const float* __restrict__ xp, unsigned char* __restrict__ sp){
  int i4 = blockIdx.x*256 + threadIdx.x;     // < CHW/4
  float4 v = {0.f,0.f,0.f,0.f};
  #pragma unroll
  for (int t = 0; t < 16; ++t){
    float4 z = *(const float4*)&xp[(size_t)t*CHW + (size_t)i4*4];
    v.x = 0.5f*(v.x + z.x); v.y = 0.5f*(v.y + z.y);
    v.z = 0.5f*(v.z + z.z); v.w = 0.5f*(v.w + z.w);
    uchar4 s;
    s.x = (v.x >= 1.0f); s.y = (v.y >= 1.0f); s.z = (v.z >= 1.0f); s.w = (v.w >= 1.0f);
    *(uchar4*)&sp[(size_t)t*CHW + (size_t)i4*4] = s;
    v.x = s.x ? 0.f : v.x; v.y = s.y ? 0.f : v.y;
    v.z = s.z ? 0.f : v.z; v.w = s.w ? 0.f : v.w;
  }
}

// ---------------- dense 3x3 conv v7: 8co/thread (SGPR weights), 32co blocks, ks=3 ----------------
// wave -> co-oct; lane = hl*8+wq (wq<7 active). Block: 32co x 8h x 56w over 32 ci.
// blockIdx.y = cog + 3*ks; partials -> outP[ks], raw (no bias/silu).
#define CIC3 8
__global__ __launch_bounds__(256) void k_conv7(const unsigned char* __restrict__ spk, const float* __restrict__ cw,
                                               float* __restrict__ outP0, float* __restrict__ outP1,
                                               float* __restrict__ outP2){
  int b = blockIdx.x;
  int cog = blockIdx.y % 3, ks = blockIdx.y / 3;
  int hb = blockIdx.z;
  int co0 = cog*32, h0 = hb*8;
  int tid = threadIdx.x;
  int wid = tid >> 6, lane = tid & 63;
  int hl = lane >> 3, wq = lane & 7;         // wq<7 active
  int coo = __builtin_amdgcn_readfirstlane(wid);
  __shared__ float xl[CIC3*10*68];           // [ci][row 0..9][col, stride 68]
  float acc[8][8];
  #pragma unroll
  for (int j = 0; j < 8; ++j)
    #pragma unroll
    for (int q = 0; q < 8; ++q) acc[j][q] = 0.f;

  for (int cc = ks*4; cc < ks*4 + 4; ++cc){
    __syncthreads();
    for (int i = tid; i < CIC3*10*58; i += 256){
      int ci = i / 580, rem = i % 580;
      int hh = rem / 58, ww = rem % 58;
      int sh = h0 - 1 + hh, sw = ww - 1;
      float v = 0.f;
      if (sh >= 0 && sh < 56 && sw >= 0 && sw < 56)
        v = (float)spk[(((size_t)b*96 + cc*CIC3 + ci)*56 + sh)*56 + sw];
      xl[ci*680 + hh*68 + ww] = v;
    }
    __syncthreads();
    for (int ci = 0; ci < CIC3; ++ci){
      int cig = cc*CIC3 + ci;
      // wave-uniform weight loads -> SGPRs (8 co x 9 taps)
      float wj[9][8];
      #pragma unroll
      for (int tap = 0; tap < 9; ++tap)
        #pragma unroll
        for (int j = 0; j < 8; ++j)
          wj[tap][j] = cw[(((size_t)(co0 + coo*8 + j))*96 + cig)*9 + tap];
      float xr[3][10];
      int base = ci*680 + hl*68 + wq*8;
      #pragma unroll
      for (int dh = 0; dh < 3; ++dh){
        float4 a = *(const float4*)&xl[base + dh*68];
        float4 c = *(const float4*)&xl[base + dh*68 + 4];
        float2 e = *(const float2*)&xl[base + dh*68 + 8];
        xr[dh][0] = a.x; xr[dh][1] = a.y; xr[dh][2] = a.z; xr[dh][3] = a.w;
        xr[dh][4] = c.x; xr[dh][5] = c.y; xr[dh][6] = c.z; xr[dh][7] = c.w;
        xr[dh][8] = e.x; xr[dh][9] = e.y;
      }
      #pragma unroll
      for (int tap = 0; tap < 9; ++tap){
        const int dh = tap/3, dw = tap%3;
        #pragma unroll
        for (int q = 0; q < 8; ++q){
          float xv = xr[dh][q + dw];
          acc[0][q] = fmaf(xv, wj[tap][0], acc[0][q]);
          acc[1][q] = fmaf(xv, wj[tap][1], acc[1][q]);
          acc[2][q] = fmaf(xv, wj[tap][2], acc[2][q]);
          acc[3][q] = fmaf(xv, wj[tap][3], acc[3][q]);
          acc[4][q] = fmaf(xv, wj[tap][4], acc[4][q]);
          acc[5][q] = fmaf(xv, wj[tap][5], acc[5][q]);
          acc[6][q] = fmaf(xv, wj[tap][6], acc[6][q]);
          acc[7][q] = fmaf(xv, wj[tap][7], acc[7][q]);
        }
      }
    }
  }
  if (wq < 7){
    float* outp = (ks == 0) ? outP0 : (ks == 1) ? outP1 : outP2;
    #pragma unroll
    for (int j = 0; j < 8; ++j){
      int co = co0 + coo*8 + j;
      float4 o0, o1;
      o0.x = acc[j][0]; o0.y = acc[j][1]; o0.z = acc[j][2]; o0.w = acc[j][3];
      o1.x = acc[j][4]; o1.y = acc[j][5]; o1.z = acc[j][6]; o1.w = acc[j][7];
      float* op = &outp[(((size_t)b*96 + co)*56 + h0 + hl)*56 + wq*8];
      *(float4*)op = o0;
      *(float4*)(op + 4) = o1;
    }
  }
}

// ---------------- depthwise 3x3 + silu, writes row-major and transposed ----------------
__global__ __launch_bounds__(256) void k_dwconv(const float* __restrict__ xin, const float* __restrict__ dwW,
                                                float* __restrict__ out, float* __restrict__ outT){
  int bd = blockIdx.x;           // b*96+d
  int d = bd % 96;
  const float* ip = xin + (size_t)bd*Lpx;
  __shared__ float pl[Lpx];
  __shared__ float po[Lpx + 56];
  int tid = threadIdx.x;
  for (int i = tid; i < Lpx; i += 256) pl[i] = ip[i];
  float w9[9];
  #pragma unroll
  for (int t = 0; t < 9; ++t) w9[t] = dwW[d*9 + t];
  __syncthreads();
  for (int i = tid; i < Lpx; i += 256){
    int h = i / 56, w = i % 56;
    float s = 0.f;
    #pragma unroll
    for (int tap = 0; tap < 9; ++tap){
      int hh = h + tap/3 - 1, ww = w + tap%3 - 1;
      if (hh >= 0 && hh < 56 && ww >= 0 && ww < 56) s = fmaf(pl[hh*56 + ww], w9[tap], s);
    }
    po[i + i/56] = siluf_(s);
  }
  __syncthreads();
  float* op  = out  + (size_t)bd*Lpx;
  float* otp = outT + (size_t)bd*Lpx;
  for (int i = tid; i < Lpx; i += 256){
    op[i] = po[i + i/56];
    int q = (i % 56)*56 + i/56;
    otp[i] = po[q + q/56];        // stride-57 LDS read: conflict-free
  }
}

// ---------------- per-pixel 96->(4k x 8r) projections, row-major and transposed ----------------
__global__ __launch_bounds__(256) void k_proj(const float* __restrict__ xss, const float* __restrict__ xpw,
                                              float* __restrict__ PROJ, float* __restrict__ PROJT){
  int b = blockIdx.x / 56, h = blockIdx.x % 56;
  __shared__ float lx[96*56];    // [d][w]
  __shared__ float lw[32*96];    // [kr][d]
  int tid = threadIdx.x;
  const float* xb = xss + (size_t)b*CHW + h*56;
  for (int i = tid; i < 96*56; i += 256){
    int d = i / 56, w = i % 56;
    lx[i] = xb[(size_t)d*Lpx + w];
  }
  for (int i = tid; i < 32*96; i += 256) lw[i] = xpw[i];
  __syncthreads();
  for (int o = tid; o < 32*56; o += 256){
    int w = o % 56, kr = o / 56;
    float s = 0.f;
    for (int d = 0; d < 96; ++d) s = fmaf(lx[d*56 + w], lw[kr*96 + d], s);
    size_t base = ((size_t)b*32 + kr)*Lpx;
    PROJ[base + h*56 + w] = s;
    PROJT[base + w*56 + h] = s;
  }
}

// ---------------- block-parallel bidirectional selective scan v3 ----------------
__global__ __launch_bounds__(256) void k_scan3(const float* __restrict__ x_rm, const float* __restrict__ x_cm,
                                               const float* __restrict__ PROJ, const float* __restrict__ PROJT,
                                               const float* __restrict__ dtw_all, const float* __restrict__ dtb_all,
                                               const float* __restrict__ Alog, const float* __restrict__ Dall,
                                               float* __restrict__ out0, float* __restrict__ out1){
  int bd = blockIdx.x; int b = bd / 96, d = bd % 96;
  int klo = blockIdx.y;
  const float* xv = (klo == 0 ? x_rm : x_cm) + (size_t)bd*Lpx;
  const float* PR = (klo == 0 ? PROJ : PROJT);
  float* yo = (klo == 0 ? out0 : out1) + (size_t)bd*Lpx;
  int kA = klo, kB = klo + 2;
  const float L2E = 1.44269504f, LN2 = 0.69314718f;

  float dwA[6], dwB[6];
  #pragma unroll
  for (int r = 0; r < 6; ++r){ dwA[r] = dtw_all[(kA*96 + d)*6 + r]; dwB[r] = dtw_all[(kB*96 + d)*6 + r]; }
  float biA = dtb_all[kA*96 + d], biB = dtb_all[kB*96 + d];
  float AA = -expf(Alog[kA*96 + d]) * L2E;
  float AB = -expf(Alog[kB*96 + d]) * L2E;
  float Dsum = Dall[kA*96 + d] + Dall[kB*96 + d];
  const float* pA = PR + ((size_t)b*32 + kA*8)*Lpx;
  const float* pB = PR + ((size_t)b*32 + kB*8)*Lpx;

  __shared__ float u[NPAD];
  __shared__ float v[NPAD];
  __shared__ float yacc[Lpx + 56];
  __shared__ float wag[8];

  int tid = threadIdx.x;
  int lane = tid & 63, wv = tid >> 6;
  int base = tid * 13;
  float la[13], lb[13];

  // ======== direction A (forward in p) ========
  for (int i = tid; i < Lpx; i += 256){
    float z = biA;
    #pragma unroll
    for (int r = 0; r < 6; ++r) z = fmaf(dwA[r], pA[(size_t)r*Lpx + i], z);
    float t = exp2f(-fabsf(z) * L2E);
    float dt = fmaxf(z, 0.f) + LN2 * log2f(1.f + t);
    u[i] = exp2f(dt * AA);
    v[i] = dt * pA[(size_t)6*Lpx + i] * xv[i];
  }
  for (int i = Lpx + tid; i < NPAD; i += 256){ u[i] = 1.f; v[i] = 0.f; }
  __syncthreads();

  {
    float a = 1.f, bb = 0.f;
    #pragma unroll
    for (int j = 0; j < 13; ++j){
      float da = u[base + j], db = v[base + j];
      bb = fmaf(da, bb, db);
      a *= da;
      la[j] = a; lb[j] = bb;
    }
    float aT = a, bT = bb;
    #pragma unroll
    for (int off = 1; off < 64; off <<= 1){
      float ap = __shfl_up(aT, off), bp = __shfl_up(bT, off);
      if (lane >= off){ bT = fmaf(aT, bp, bT); aT *= ap; }
    }
    if (lane == 63){ wag[wv] = aT; wag[4 + wv] = bT; }
    float a_ex = __shfl_up(aT, 1), b_ex = __shfl_up(bT, 1);
    if (lane == 0){ a_ex = 1.f; b_ex = 0.f; }
    __syncthreads();
    float hw = 0.f;
    for (int j = 0; j < wv; ++j) hw = fmaf(wag[j], hw, wag[4 + j]);
    float hin = fmaf(a_ex, hw, b_ex);
    #pragma unroll
    for (int j = 0; j < 13; ++j)
      v[base + j] = fmaf(la[j], hin, lb[j]);
  }
  __syncthreads();
  for (int i = tid; i < Lpx; i += 256){
    float C = pA[(size_t)7*Lpx + i];
    yacc[i + i/56] = fmaf(C, v[i], Dsum * xv[i]);
  }
  __syncthreads();

  // ======== direction B (reverse in p) ========
  for (int i = tid; i < Lpx; i += 256){
    float z = biB;
    #pragma unroll
    for (int r = 0; r < 6; ++r) z = fmaf(dwB[r], pB[(size_t)r*Lpx + i], z);
    float t = exp2f(-fabsf(z) * L2E);
    float dt = fmaxf(z, 0.f) + LN2 * log2f(1.f + t);
    u[i] = exp2f(dt * AB);
    v[i] = dt * pB[(size_t)6*Lpx + i] * xv[i];
  }
  for (int i = Lpx + tid; i < NPAD; i += 256){ u[i] = 1.f; v[i] = 0.f; }
  __syncthreads();

  {
    float a = 1.f, bb = 0.f;
    #pragma unroll
    for (int j = 12; j >= 0; --j){
      float da = u[base + j], db = v[base + j];
      bb = fmaf(da, bb, db);
      a *= da;
      la[j] = a; lb[j] = bb;
    }
    float aT = a, bT = bb;
    #pragma unroll
    for (int off = 1; off < 64; off <<= 1){
      float ap = __shfl_down(aT, off), bp = __shfl_down(bT, off);
      if (lane + off < 64){ bT = fmaf(aT, bp, bT); aT *= ap; }
    }
    if (lane == 0){ wag[wv] = aT; wag[4 + wv] = bT; }
    float a_ex = __shfl_down(aT, 1), b_ex = __shfl_down(bT, 1);
    if (lane == 63){ a_ex = 1.f; b_ex = 0.f; }
    __syncthreads();
    float hw = 0.f;
    for (int j = 3; j > wv; --j) hw = fmaf(wag[j], hw, wag[4 + j]);
    float hin = fmaf(a_ex, hw, b_ex);
    #pragma unroll
    for (int j = 0; j < 13; ++j)
      v[base + j] = fmaf(la[j], hin, lb[j]);
  }
  __syncthreads();
  for (int i = tid; i < Lpx; i += 256){
    float C = pB[(size_t)7*Lpx + i];
    yacc[i + i/56] = fmaf(C, v[i], yacc[i + i/56]);
  }
  __syncthreads();

  if (klo == 0){
    for (int i = tid; i < Lpx; i += 256)
      yo[i] = yacc[i + i/56];
  } else {
    for (int i = tid; i < Lpx; i += 256){
      int q = (i % 56)*56 + i/56;
      yo[i] = yacc[q + q/56];
    }
  }
}

// ---------------- combine ya+yb, LayerNorm over channels (float4) ----------------
__global__ __launch_bounds__(256) void k_ln(const float* __restrict__ ya, const float* __restrict__ yb,
                                            const float* __restrict__ g, const float* __restrict__ be,
                                            float* __restrict__ out){
  int i4 = blockIdx.x*256 + threadIdx.x;    // < 16*784
  int b = i4 / 784, p = (i4 % 784) * 4;
  const float* ap = ya + (size_t)b*CHW + p;
  const float* bp = yb + (size_t)b*CHW + p;
  float4 s = {0.f,0.f,0.f,0.f};
  for (int d = 0; d < 96; ++d){
    float4 av = *(const float4*)&ap[(size_t)d*Lpx];
    float4 bv = *(const float4*)&bp[(size_t)d*Lpx];
    s.x += av.x + bv.x; s.y += av.y + bv.y; s.z += av.z + bv.z; s.w += av.w + bv.w;
  }
  float4 mu; mu.x = s.x*(1.f/96.f); mu.y = s.y*(1.f/96.f); mu.z = s.z*(1.f/96.f); mu.w = s.w*(1.f/96.f);
  float4 ss = {0.f,0.f,0.f,0.f};
  for (int d = 0; d < 96; ++d){
    float4 av = *(const float4*)&ap[(size_t)d*Lpx];
    float4 bv = *(const float4*)&bp[(size_t)d*Lpx];
    float vx = av.x + bv.x - mu.x, vy = av.y + bv.y - mu.y;
    float vz = av.z + bv.z - mu.z, vw = av.w + bv.w - mu.w;
    ss.x = fmaf(vx,vx,ss.x); ss.y = fmaf(vy,vy,ss.y); ss.z = fmaf(vz,vz,ss.z); ss.w = fmaf(vw,vw,ss.w);
  }
  float4 rs;
  rs.x = 1.f/sqrtf(ss.x*(1.f/96.f) + 1e-5f); rs.y = 1.f/sqrtf(ss.y*(1.f/96.f) + 1e-5f);
  rs.z = 1.f/sqrtf(ss.z*(1.f/96.f) + 1e-5f); rs.w = 1.f/sqrtf(ss.w*(1.f/96.f) + 1e-5f);
  float* op = out + (size_t)b*CHW + p;
  for (int d = 0; d < 96; ++d){
    float4 av = *(const float4*)&ap[(size_t)d*Lpx];
    float4 bv = *(const float4*)&bp[(size_t)d*Lpx];
    float gd = g[d], bd = be[d];
    float4 o;
    o.x = (av.x + bv.x - mu.x)*rs.x*gd + bd;
    o.y = (av.y + bv.y - mu.y)*rs.y*gd + bd;
    o.z = (av.z + bv.z - mu.z)*rs.z*gd + bd;
    o.w = (av.w + bv.w - mu.w)*rs.w*gd + bd;
    *(float4*)&op[(size_t)d*Lpx] = o;
  }
}

// ---------------- LIF over T=4 + multiply with original x (float4) ----------------
__global__ __launch_bounds__(256) void k_lif2(const float* __restrict__ yo, const float* __restrict__ x0,
                                              float* __restrict__ out){
  const int stride4 = 301056;   // B*C*L/4
  int i4 = blockIdx.x*256 + threadIdx.x;
  float4 v = {0.f,0.f,0.f,0.f};
  #pragma unroll
  for (int t = 0; t < 4; ++t){
    float4 z = *(const float4*)&yo[((size_t)t*stride4 + i4)*4];
    float4 xv = *(const float4*)&x0[((size_t)t*stride4 + i4)*4];
    v.x = 0.5f*(v.x + z.x); v.y = 0.5f*(v.y + z.y);
    v.z = 0.5f*(v.z + z.z); v.w = 0.5f*(v.w + z.w);
    float4 o;
    o.x = (v.x >= 1.0f) ? xv.x : 0.f; o.y = (v.y >= 1.0f) ? xv.y : 0.f;
    o.z = (v.z >= 1.0f) ? xv.z : 0.f; o.w = (v.w >= 1.0f) ? xv.w : 0.f;
    v.x = (v.x >= 1.0f) ? 0.f : v.x; v.y = (v.y >= 1.0f) ? 0.f : v.y;
    v.z = (v.z >= 1.0f) ? 0.f : v.z; v.w = (v.w >= 1.0f) ? 0.f : v.w;
    *(float4*)&out[((size_t)t*stride4 + i4)*4] = o;
  }
}

extern "C" void kernel_launch(void* const* d_in, const int* in_sizes, int n_in,
                              void* d_out, int out_size, void* d_ws, size_t ws_size,
                              hipStream_t stream) {
  const float* x    = (const float*)d_in[0];
  const float* ipw  = (const float*)d_in[1];
  const float* ipb  = (const float*)d_in[2];
  const float* cw   = (const float*)d_in[3];
  const float* cb   = (const float*)d_in[4];
  const float* siw  = (const float*)d_in[5];
  const float* scw  = (const float*)d_in[6];
  const float* xpw  = (const float*)d_in[7];
  const float* dtw  = (const float*)d_in[8];
  const float* dtb  = (const float*)d_in[9];
  const float* alog = (const float*)d_in[10];
  const float* dsv  = (const float*)d_in[11];
  const float* lng  = (const float*)d_in[12];
  const float* lnb  = (const float*)d_in[13];
  const float* opw  = (const float*)d_in[14];

  float* s1 = (float*)d_ws;
  float* s2 = s1 + SZn;
  float* s3 = s2 + SZn;
  float* s4 = s3 + SZn;
  float* pr  = s4 + SZn;
  float* prT = pr + PRJ;

  // 1) in_proj -> xp in s1
  k_matmul<<<784, 256, 0, stream>>>(x, ipw, ipb, s1);
  // 2) LIF over 16 steps -> uchar spikes in s2
  k_lif1<<<294, 256, 0, stream>>>(s1, (unsigned char*)s2);
  // 3) dense 3x3 conv, K-split(3) partials -> s1, s3, s4
  k_conv7<<<dim3(16, 9, 7), 256, 0, stream>>>((const unsigned char*)s2, cw, s1, s3, s4);
  // 4) merge(bias+silu) + ssm_in matmul -> s2
  k_matmulM<<<784, 256, 0, stream>>>(s1, s3, s4, cb, siw, s2);
  // 5) depthwise conv + silu -> xss rm in s1, cm in s3
  k_dwconv<<<1536, 256, 0, stream>>>(s2, scw, s1, s3);
  // 6) projections (pixel-indexed, both layouts)
  k_proj<<<896, 256, 0, stream>>>(s1, xpw, pr, prT);
  // 7) both scan dir-pairs: ya -> s2, yb(row-major) -> s4
  k_scan3<<<dim3(1536, 2), 256, 0, stream>>>(s1, s3, pr, prT, dtw, dtb, alog, dsv, s2, s4);
  // 8) combine + LayerNorm -> s3
  k_ln<<<49, 256, 0, stream>>>(s2, s4, lng, lnb, s3);
  // 9) out_proj -> s2
  k_matmul<<<784, 256, 0, stream>>>(s3, opw, nullptr, s2);
  // 10) LIF over T=4, multiply with x -> d_out
  k_lif2<<<1176, 256, 0, stream>>>(s2, x, (float*)d_out);
}

// Round 15
// 434.930 us; speedup vs baseline: 2.2906x; 1.0943x over previous
//
#include <hip/hip_runtime.h>
#include <math.h>

#define TBn 16
#define Lpx 3136
#define CHW 301056      // 96*3136
#define SZn 4816896     // 16*96*3136
#define PRJ 1605632     // 16*32*3136
#define NPAD 3328       // 256*13

__device__ __forceinline__ float siluf_(float z){ return z / (1.f + expf(-z)); }

// ---------------- per-pixel channel matmul v2: full weight tile, ci unrolled x4 ----------------
__global__ __launch_bounds__(256) void k_matmul(const float* __restrict__ in, const float* __restrict__ Wm,
                                                const float* __restrict__ bias, float* __restrict__ out){
  int blk = blockIdx.x;
  int n = blk / 49, pt = blk % 49, p0 = pt * 64;
  __shared__ float lx[96*64];     // [ci][px]
  __shared__ float wl[96*100];    // [co][ci], stride 100
  int tid = threadIdx.x;
  const float* inb = in + (size_t)n*CHW;
  for (int i = tid; i < 96*64; i += 256){
    int ci = i >> 6, px = i & 63;
    lx[i] = inb[(size_t)ci*Lpx + p0 + px];
  }
  for (int i = tid; i < 96*96; i += 256){
    int co = i / 96, ci = i % 96;
    wl[co*100 + ci] = Wm[i];
  }
  int px_t = tid & 15, co_t = tid >> 4;
  float acc[6][4];
  #pragma unroll
  for (int j = 0; j < 6; ++j){
    float b = bias ? bias[co_t*6 + j] : 0.f;
    #pragma unroll
    for (int q = 0; q < 4; ++q) acc[j][q] = b;
  }
  __syncthreads();
  for (int c4 = 0; c4 < 24; ++c4){
    float4 xv0 = *(const float4*)&lx[(c4*4 + 0)*64 + px_t*4];
    float4 xv1 = *(const float4*)&lx[(c4*4 + 1)*64 + px_t*4];
    float4 xv2 = *(const float4*)&lx[(c4*4 + 2)*64 + px_t*4];
    float4 xv3 = *(const float4*)&lx[(c4*4 + 3)*64 + px_t*4];
    #pragma unroll
    for (int j = 0; j < 6; ++j){
      float4 wv = *(const float4*)&wl[(co_t*6 + j)*100 + c4*4];
      acc[j][0] = fmaf(wv.x, xv0.x, acc[j][0]); acc[j][1] = fmaf(wv.x, xv0.y, acc[j][1]);
      acc[j][2] = fmaf(wv.x, xv0.z, acc[j][2]); acc[j][3] = fmaf(wv.x, xv0.w, acc[j][3]);
      acc[j][0] = fmaf(wv.y, xv1.x, acc[j][0]); acc[j][1] = fmaf(wv.y, xv1.y, acc[j][1]);
      acc[j][2] = fmaf(wv.y, xv1.z, acc[j][2]); acc[j][3] = fmaf(wv.y, xv1.w, acc[j][3]);
      acc[j][0] = fmaf(wv.z, xv2.x, acc[j][0]); acc[j][1] = fmaf(wv.z, xv2.y, acc[j][1]);
      acc[j][2] = fmaf(wv.z, xv2.z, acc[j][2]); acc[j][3] = fmaf(wv.z, xv2.w, acc[j][3]);
      acc[j][0] = fmaf(wv.w, xv3.x, acc[j][0]); acc[j][1] = fmaf(wv.w, xv3.y, acc[j][1]);
      acc[j][2] = fmaf(wv.w, xv3.z, acc[j][2]); acc[j][3] = fmaf(wv.w, xv3.w, acc[j][3]);
    }
  }
  float* ob = out + (size_t)n*CHW + p0 + px_t*4;
  #pragma unroll
  for (int j = 0; j < 6; ++j){
    float4 v; v.x = acc[j][0]; v.y = acc[j][1]; v.z = acc[j][2]; v.w = acc[j][3];
    *(float4*)&ob[(size_t)(co_t*6 + j)*Lpx] = v;
  }
}

// ---------------- matmul merge variant: in = silu(pA+pB+pC+cb) ----------------
__global__ __launch_bounds__(256) void k_matmulM(const float* __restrict__ pA, const float* __restrict__ pB,
                                                 const float* __restrict__ pC, const float* __restrict__ cbias,
                                                 const float* __restrict__ Wm, float* __restrict__ out){
  int blk = blockIdx.x;
  int n = blk / 49, pt = blk % 49, p0 = pt * 64;
  __shared__ float lx[96*64];
  __shared__ float wl[96*100];
  int tid = threadIdx.x;
  const float* inA = pA + (size_t)n*CHW;
  const float* inB = pB + (size_t)n*CHW;
  const float* inC = pC + (size_t)n*CHW;
  for (int i = tid; i < 96*64; i += 256){
    int ci = i >> 6, px = i & 63;
    size_t off = (size_t)ci*Lpx + p0 + px;
    float z = inA[off] + inB[off] + inC[off] + cbias[ci];
    lx[i] = siluf_(z);
  }
  for (int i = tid; i < 96*96; i += 256){
    int co = i / 96, ci = i % 96;
    wl[co*100 + ci] = Wm[i];
  }
  int px_t = tid & 15, co_t = tid >> 4;
  float acc[6][4];
  #pragma unroll
  for (int j = 0; j < 6; ++j)
    #pragma unroll
    for (int q = 0; q < 4; ++q) acc[j][q] = 0.f;
  __syncthreads();
  for (int c4 = 0; c4 < 24; ++c4){
    float4 xv0 = *(const float4*)&lx[(c4*4 + 0)*64 + px_t*4];
    float4 xv1 = *(const float4*)&lx[(c4*4 + 1)*64 + px_t*4];
    float4 xv2 = *(const float4*)&lx[(c4*4 + 2)*64 + px_t*4];
    float4 xv3 = *(const float4*)&lx[(c4*4 + 3)*64 + px_t*4];
    #pragma unroll
    for (int j = 0; j < 6; ++j){
      float4 wv = *(const float4*)&wl[(co_t*6 + j)*100 + c4*4];
      acc[j][0] = fmaf(wv.x, xv0.x, acc[j][0]); acc[j][1] = fmaf(wv.x, xv0.y, acc[j][1]);
      acc[j][2] = fmaf(wv.x, xv0.z, acc[j][2]); acc[j][3] = fmaf(wv.x, xv0.w, acc[j][3]);
      acc[j][0] = fmaf(wv.y, xv1.x, acc[j][0]); acc[j][1] = fmaf(wv.y, xv1.y, acc[j][1]);
      acc[j][2] = fmaf(wv.y, xv1.z, acc[j][2]); acc[j][3] = fmaf(wv.y, xv1.w, acc[j][3]);
      acc[j][0] = fmaf(wv.z, xv2.x, acc[j][0]); acc[j][1] = fmaf(wv.z, xv2.y, acc[j][1]);
      acc[j][2] = fmaf(wv.z, xv2.z, acc[j][2]); acc[j][3] = fmaf(wv.z, xv2.w, acc[j][3]);
      acc[j][0] = fmaf(wv.w, xv3.x, acc[j][0]); acc[j][1] = fmaf(wv.w, xv3.y, acc[j][1]);
      acc[j][2] = fmaf(wv.w, xv3.z, acc[j][2]); acc[j][3] = fmaf(wv.w, xv3.w, acc[j][3]);
    }
  }
  float* ob = out + (size_t)n*CHW + p0 + px_t*4;
  #pragma unroll
  for (int j = 0; j < 6; ++j){
    float4 v; v.x = acc[j][0]; v.y = acc[j][1]; v.z = acc[j][2]; v.w = acc[j][3];
    *(float4*)&ob[(size_t)(co_t*6 + j)*Lpx] = v;
  }
}

// ---------------- fused LayerNorm + out_proj matmul ----------------
// stages y = ya+yb into LDS, two-pass LN over channels per pixel, then 96x96 matmul.
__global__ __launch_bounds__(256) void k_matmulLN(const float* __restrict__ ya, const float* __restrict__ yb,
                                                  const float* __restrict__ g, const float* __restrict__ be,
                                                  const float* __restrict__ Wm, float* __restrict__ out){
  int blk = blockIdx.x;
  int n = blk / 49, pt = blk % 49, p0 = pt * 64;
  __shared__ float lx[96*64];
  __shared__ float wl[96*100];
  __shared__ float red[4*64];
  __shared__ float muS[64], rsS[64];
  int tid = threadIdx.x;
  const float* inA = ya + (size_t)n*CHW;
  const float* inB = yb + (size_t)n*CHW;
  for (int i = tid; i < 96*64; i += 256){
    int ci = i >> 6, px = i & 63;
    size_t off = (size_t)ci*Lpx + p0 + px;
    lx[i] = inA[off] + inB[off];
  }
  for (int i = tid; i < 96*96; i += 256){
    int co = i / 96, ci = i % 96;
    wl[co*100 + ci] = Wm[i];
  }
  __syncthreads();
  int pxr = tid & 63, gq = tid >> 6;
  {
    float s = 0.f;
    for (int c = 0; c < 24; ++c) s += lx[(gq*24 + c)*64 + pxr];
    red[gq*64 + pxr] = s;
  }
  __syncthreads();
  if (tid < 64) muS[tid] = (red[tid] + red[64+tid] + red[128+tid] + red[192+tid]) * (1.f/96.f);
  __syncthreads();
  {
    float m = muS[pxr];
    float q = 0.f;
    for (int c = 0; c < 24; ++c){ float v = lx[(gq*24 + c)*64 + pxr] - m; q = fmaf(v, v, q); }
    red[gq*64 + pxr] = q;
  }
  __syncthreads();
  if (tid < 64) rsS[tid] = 1.f / sqrtf((red[tid] + red[64+tid] + red[128+tid] + red[192+tid])*(1.f/96.f) + 1e-5f);
  __syncthreads();
  for (int i = tid; i < 96*64; i += 256){
    int ci = i >> 6, ppx = i & 63;
    lx[i] = (lx[i] - muS[ppx]) * rsS[ppx] * g[ci] + be[ci];
  }
  int px_t = tid & 15, co_t = tid >> 4;
  float acc[6][4];
  #pragma unroll
  for (int j = 0; j < 6; ++j)
    #pragma unroll
    for (int q = 0; q < 4; ++q) acc[j][q] = 0.f;
  __syncthreads();
  for (int c4 = 0; c4 < 24; ++c4){
    float4 xv0 = *(const float4*)&lx[(c4*4 + 0)*64 + px_t*4];
    float4 xv1 = *(const float4*)&lx[(c4*4 + 1)*64 + px_t*4];
    float4 xv2 = *(const float4*)&lx[(c4*4 + 2)*64 + px_t*4];
    float4 xv3 = *(const float4*)&lx[(c4*4 + 3)*64 + px_t*4];
    #pragma unroll
    for (int j = 0; j < 6; ++j){
      float4 wv = *(const float4*)&wl[(co_t*6 + j)*100 + c4*4];
      acc[j][0] = fmaf(wv.x, xv0.x, acc[j][0]); acc[j][1] = fmaf(wv.x, xv0.y, acc[j][1]);
      acc[j][2] = fmaf(wv.x, xv0.z, acc[j][2]); acc[j][3] = fmaf(wv.x, xv0.w, acc[j][3]);
      acc[j][0] = fmaf(wv.y, xv1.x, acc[j][0]); acc[j][1] = fmaf(wv.y, xv1.y, acc[j][1]);
      acc[j][2] = fmaf(wv.y, xv1.z, acc[j][2]); acc[j][3] = fmaf(wv.y, xv1.w, acc[j][3]);
      acc[j][0] = fmaf(wv.z, xv2.x, acc[j][0]); acc[j][1] = fmaf(wv.z, xv2.y, acc[j][1]);
      acc[j][2] = fmaf(wv.z, xv2.z, acc[j][2]); acc[j][3] = fmaf(wv.z, xv2.w, acc[j][3]);
      acc[j][0] = fmaf(wv.w, xv3.x, acc[j][0]); acc[j][1] = fmaf(wv.w, xv3.y, acc[j][1]);
      acc[j][2] = fmaf(wv.w, xv3.z, acc[j][2]); acc[j][3] = fmaf(wv.w, xv3.w, acc[j][3]);
    }
  }
  float* ob = out + (size_t)n*CHW + p0 + px_t*4;
  #pragma unroll
  for (int j = 0; j < 6; ++j){
    float4 v; v.x = acc[j][0]; v.y = acc[j][1]; v.z = acc[j][2]; v.w = acc[j][3];
    *(float4*)&ob[(size_t)(co_t*6 + j)*Lpx] = v;
  }
}

// ---------------- LIF over 16 steps, float4, uchar spike output ----------------
__global__ __launch_bounds__(256) void k_lif1(const float* __restrict__ xp, unsigned char* __restrict__ sp){
  int i4 = blockIdx.x*256 + threadIdx.x;     // < CHW/4
  float4 v = {0.f,0.f,0.f,0.f};
  #pragma unroll
  for (int t = 0; t < 16; ++t){
    float4 z = *(const float4*)&xp[(size_t)t*CHW + (size_t)i4*4];
    v.x = 0.5f*(v.x + z.x); v.y = 0.5f*(v.y + z.y);
    v.z = 0.5f*(v.z + z.z); v.w = 0.5f*(v.w + z.w);
    uchar4 s;
    s.x = (v.x >= 1.0f); s.y = (v.y >= 1.0f); s.z = (v.z >= 1.0f); s.w = (v.w >= 1.0f);
    *(uchar4*)&sp[(size_t)t*CHW + (size_t)i4*4] = s;
    v.x = s.x ? 0.f : v.x; v.y = s.y ? 0.f : v.y;
    v.z = s.z ? 0.f : v.z; v.w = s.w ? 0.f : v.w;
  }
}

// ---------------- dense 3x3 conv v8: conv7 + async-STAGE split (load-early / write-late) ----------------
#define CIC3 8
#define NST 19
__global__ __launch_bounds__(256) void k_conv8(const unsigned char* __restrict__ spk, const float* __restrict__ cw,
                                               float* __restrict__ outP0, float* __restrict__ outP1,
                                               float* __restrict__ outP2){
  int b = blockIdx.x;
  int cog = blockIdx.y % 3, ks = blockIdx.y / 3;
  int hb = blockIdx.z;
  int co0 = cog*32, h0 = hb*8;
  int tid = threadIdx.x;
  int wid = tid >> 6, lane = tid & 63;
  int hl = lane >> 3, wq = lane & 7;         // wq<7 active for stores
  int coo = __builtin_amdgcn_readfirstlane(wid);
  __shared__ float xl[CIC3*10*68];           // [ci][row 0..9][col, stride 68]
  const unsigned char* spb = spk + (size_t)b*96*3136;
  float acc[8][8];
  #pragma unroll
  for (int j = 0; j < 8; ++j)
    #pragma unroll
    for (int q = 0; q < 8; ++q) acc[j][q] = 0.f;

  // prologue: stage first chunk directly
  {
    int cc = ks*4;
    #pragma unroll
    for (int j = 0; j < NST; ++j){
      int i = tid + j*256;
      if (i < CIC3*10*58){
        int ci = i / 580, rem = i % 580;
        int hh = rem / 58, ww = rem % 58;
        int sh = h0 - 1 + hh, sw = ww - 1;
        float v = 0.f;
        if (sh >= 0 && sh < 56 && sw >= 0 && sw < 56)
          v = (float)spb[(size_t)(cc*CIC3 + ci)*3136 + sh*56 + sw];
        xl[ci*680 + hh*68 + ww] = v;
      }
    }
  }
  __syncthreads();

  for (int s = 0; s < 4; ++s){
    int cc = ks*4 + s;
    // issue next-chunk loads into registers (latency hides under compute below)
    float f2[NST];
    if (s < 3){
      int cn = cc + 1;
      #pragma unroll
      for (int j = 0; j < NST; ++j){
        int i = tid + j*256;
        float v = 0.f;
        if (i < CIC3*10*58){
          int ci = i / 580, rem = i % 580;
          int hh = rem / 58, ww = rem % 58;
          int sh = h0 - 1 + hh, sw = ww - 1;
          if (sh >= 0 && sh < 56 && sw >= 0 && sw < 56)
            v = (float)spb[(size_t)(cn*CIC3 + ci)*3136 + sh*56 + sw];
        }
        f2[j] = v;
      }
    }
    // compute current tile
    for (int ci = 0; ci < CIC3; ++ci){
      int cig = cc*CIC3 + ci;
      float wj[9][8];
      #pragma unroll
      for (int tap = 0; tap < 9; ++tap)
        #pragma unroll
        for (int j = 0; j < 8; ++j)
          wj[tap][j] = cw[(((size_t)(co0 + coo*8 + j))*96 + cig)*9 + tap];
      float xr[3][10];
      int base = ci*680 + hl*68 + wq*8;
      #pragma unroll
      for (int dh = 0; dh < 3; ++dh){
        float4 a = *(const float4*)&xl[base + dh*68];
        float4 c = *(const float4*)&xl[base + dh*68 + 4];
        float2 e = *(const float2*)&xl[base + dh*68 + 8];
        xr[dh][0] = a.x; xr[dh][1] = a.y; xr[dh][2] = a.z; xr[dh][3] = a.w;
        xr[dh][4] = c.x; xr[dh][5] = c.y; xr[dh][6] = c.z; xr[dh][7] = c.w;
        xr[dh][8] = e.x; xr[dh][9] = e.y;
      }
      #pragma unroll
      for (int tap = 0; tap < 9; ++tap){
        const int dh = tap/3, dw = tap%3;
        #pragma unroll
        for (int q = 0; q < 8; ++q){
          float xv = xr[dh][q + dw];
          acc[0][q] = fmaf(xv, wj[tap][0], acc[0][q]);
          acc[1][q] = fmaf(xv, wj[tap][1], acc[1][q]);
          acc[2][q] = fmaf(xv, wj[tap][2], acc[2][q]);
          acc[3][q] = fmaf(xv, wj[tap][3], acc[3][q]);
          acc[4][q] = fmaf(xv, wj[tap][4], acc[4][q]);
          acc[5][q] = fmaf(xv, wj[tap][5], acc[5][q]);
          acc[6][q] = fmaf(xv, wj[tap][6], acc[6][q]);
          acc[7][q] = fmaf(xv, wj[tap][7], acc[7][q]);
        }
      }
    }
    __syncthreads();     // all waves done reading xl
    if (s < 3){
      #pragma unroll
      for (int j = 0; j < NST; ++j){
        int i = tid + j*256;
        if (i < CIC3*10*58){
          int ci = i / 580, rem = i % 580;
          int hh = rem / 58, ww = rem % 58;
          xl[ci*680 + hh*68 + ww] = f2[j];
        }
      }
      __syncthreads();   // writes visible
    }
  }
  if (wq < 7){
    float* outp = (ks == 0) ? outP0 : (ks == 1) ? outP1 : outP2;
    #pragma unroll
    for (int j = 0; j < 8; ++j){
      int co = co0 + coo*8 + j;
      float4 o0, o1;
      o0.x = acc[j][0]; o0.y = acc[j][1]; o0.z = acc[j][2]; o0.w = acc[j][3];
      o1.x = acc[j][4]; o1.y = acc[j][5]; o1.z = acc[j][6]; o1.w = acc[j][7];
      float* op = &outp[(((size_t)b*96 + co)*56 + h0 + hl)*56 + wq*8];
      *(float4*)op = o0;
      *(float4*)(op + 4) = o1;
    }
  }
}

// ---------------- depthwise 3x3 + silu, writes row-major and transposed ----------------
__global__ __launch_bounds__(256) void k_dwconv(const float* __restrict__ xin, const float* __restrict__ dwW,
                                                float* __restrict__ out, float* __restrict__ outT){
  int bd = blockIdx.x;           // b*96+d
  int d = bd % 96;
  const float* ip = xin + (size_t)bd*Lpx;
  __shared__ float pl[Lpx];
  __shared__ float po[Lpx + 56];
  int tid = threadIdx.x;
  for (int i = tid; i < Lpx; i += 256) pl[i] = ip[i];
  float w9[9];
  #pragma unroll
  for (int t = 0; t < 9; ++t) w9[t] = dwW[d*9 + t];
  __syncthreads();
  for (int i = tid; i < Lpx; i += 256){
    int h = i / 56, w = i % 56;
    float s = 0.f;
    #pragma unroll
    for (int tap = 0; tap < 9; ++tap){
      int hh = h + tap/3 - 1, ww = w + tap%3 - 1;
      if (hh >= 0 && hh < 56 && ww >= 0 && ww < 56) s = fmaf(pl[hh*56 + ww], w9[tap], s);
    }
    po[i + i/56] = siluf_(s);
  }
  __syncthreads();
  float* op  = out  + (size_t)bd*Lpx;
  float* otp = outT + (size_t)bd*Lpx;
  for (int i = tid; i < Lpx; i += 256){
    op[i] = po[i + i/56];
    int q = (i % 56)*56 + i/56;
    otp[i] = po[q + q/56];        // stride-57 LDS read: conflict-free
  }
}

// ---------------- per-pixel 96->(4k x 8r) projections, row-major and transposed ----------------
__global__ __launch_bounds__(256) void k_proj(const float* __restrict__ xss, const float* __restrict__ xpw,
                                              float* __restrict__ PROJ, float* __restrict__ PROJT){
  int b = blockIdx.x / 56, h = blockIdx.x % 56;
  __shared__ float lx[96*56];    // [d][w]
  __shared__ float lw[32*96];    // [kr][d]
  int tid = threadIdx.x;
  const float* xb = xss + (size_t)b*CHW + h*56;
  for (int i = tid; i < 96*56; i += 256){
    int d = i / 56, w = i % 56;
    lx[i] = xb[(size_t)d*Lpx + w];
  }
  for (int i = tid; i < 32*96; i += 256) lw[i] = xpw[i];
  __syncthreads();
  for (int o = tid; o < 32*56; o += 256){
    int w = o % 56, kr = o / 56;
    float s = 0.f;
    for (int d = 0; d < 96; ++d) s = fmaf(lx[d*56 + w], lw[kr*96 + d], s);
    size_t base = ((size_t)b*32 + kr)*Lpx;
    PROJ[base + h*56 + w] = s;
    PROJT[base + w*56 + h] = s;
  }
}

// ---------------- block-parallel bidirectional selective scan v3 ----------------
__global__ __launch_bounds__(256) void k_scan3(const float* __restrict__ x_rm, const float* __restrict__ x_cm,
                                               const float* __restrict__ PROJ, const float* __restrict__ PROJT,
                                               const float* __restrict__ dtw_all, const float* __restrict__ dtb_all,
                                               const float* __restrict__ Alog, const float* __restrict__ Dall,
                                               float* __restrict__ out0, float* __restrict__ out1){
  int bd = blockIdx.x; int b = bd / 96, d = bd % 96;
  int klo = blockIdx.y;
  const float* xv = (klo == 0 ? x_rm : x_cm) + (size_t)bd*Lpx;
  const float* PR = (klo == 0 ? PROJ : PROJT);
  float* yo = (klo == 0 ? out0 : out1) + (size_t)bd*Lpx;
  int kA = klo, kB = klo + 2;
  const float L2E = 1.44269504f, LN2 = 0.69314718f;

  float dwA[6], dwB[6];
  #pragma unroll
  for (int r = 0; r < 6; ++r){ dwA[r] = dtw_all[(kA*96 + d)*6 + r]; dwB[r] = dtw_all[(kB*96 + d)*6 + r]; }
  float biA = dtb_all[kA*96 + d], biB = dtb_all[kB*96 + d];
  float AA = -expf(Alog[kA*96 + d]) * L2E;
  float AB = -expf(Alog[kB*96 + d]) * L2E;
  float Dsum = Dall[kA*96 + d] + Dall[kB*96 + d];
  const float* pA = PR + ((size_t)b*32 + kA*8)*Lpx;
  const float* pB = PR + ((size_t)b*32 + kB*8)*Lpx;

  __shared__ float u[NPAD];
  __shared__ float v[NPAD];
  __shared__ float yacc[Lpx + 56];
  __shared__ float wag[8];

  int tid = threadIdx.x;
  int lane = tid & 63, wv = tid >> 6;
  int base = tid * 13;
  float la[13], lb[13];

  // ======== direction A (forward in p) ========
  for (int i = tid; i < Lpx; i += 256){
    float z = biA;
    #pragma unroll
    for (int r = 0; r < 6; ++r) z = fmaf(dwA[r], pA[(size_t)r*Lpx + i], z);
    float t = exp2f(-fabsf(z) * L2E);
    float dt = fmaxf(z, 0.f) + LN2 * log2f(1.f + t);
    u[i] = exp2f(dt * AA);
    v[i] = dt * pA[(size_t)6*Lpx + i] * xv[i];
  }
  for (int i = Lpx + tid; i < NPAD; i += 256){ u[i] = 1.f; v[i] = 0.f; }
  __syncthreads();

  {
    float a = 1.f, bb = 0.f;
    #pragma unroll
    for (int j = 0; j < 13; ++j){
      float da = u[base + j], db = v[base + j];
      bb = fmaf(da, bb, db);
      a *= da;
      la[j] = a; lb[j] = bb;
    }
    float aT = a, bT = bb;
    #pragma unroll
    for (int off = 1; off < 64; off <<= 1){
      float ap = __shfl_up(aT, off), bp = __shfl_up(bT, off);
      if (lane >= off){ bT = fmaf(aT, bp, bT); aT *= ap; }
    }
    if (lane == 63){ wag[wv] = aT; wag[4 + wv] = bT; }
    float a_ex = __shfl_up(aT, 1), b_ex = __shfl_up(bT, 1);
    if (lane == 0){ a_ex = 1.f; b_ex = 0.f; }
    __syncthreads();
    float hw = 0.f;
    for (int j = 0; j < wv; ++j) hw = fmaf(wag[j], hw, wag[4 + j]);
    float hin = fmaf(a_ex, hw, b_ex);
    #pragma unroll
    for (int j = 0; j < 13; ++j)
      v[base + j] = fmaf(la[j], hin, lb[j]);
  }
  __syncthreads();
  for (int i = tid; i < Lpx; i += 256){
    float C = pA[(size_t)7*Lpx + i];
    yacc[i + i/56] = fmaf(C, v[i], Dsum * xv[i]);
  }
  __syncthreads();

  // ======== direction B (reverse in p) ========
  for (int i = tid; i < Lpx; i += 256){
    float z = biB;
    #pragma unroll
    for (int r = 0; r < 6; ++r) z = fmaf(dwB[r], pB[(size_t)r*Lpx + i], z);
    float t = exp2f(-fabsf(z) * L2E);
    float dt = fmaxf(z, 0.f) + LN2 * log2f(1.f + t);
    u[i] = exp2f(dt * AB);
    v[i] = dt * pB[(size_t)6*Lpx + i] * xv[i];
  }
  for (int i = Lpx + tid; i < NPAD; i += 256){ u[i] = 1.f; v[i] = 0.f; }
  __syncthreads();

  {
    float a = 1.f, bb = 0.f;
    #pragma unroll
    for (int j = 12; j >= 0; --j){
      float da = u[base + j], db = v[base + j];
      bb = fmaf(da, bb, db);
      a *= da;
      la[j] = a; lb[j] = bb;
    }
    float aT = a, bT = bb;
    #pragma unroll
    for (int off = 1; off < 64; off <<= 1){
      float ap = __shfl_down(aT, off), bp = __shfl_down(bT, off);
      if (lane + off < 64){ bT = fmaf(aT, bp, bT); aT *= ap; }
    }
    if (lane == 0){ wag[wv] = aT; wag[4 + wv] = bT; }
    float a_ex = __shfl_down(aT, 1), b_ex = __shfl_down(bT, 1);
    if (lane == 63){ a_ex = 1.f; b_ex = 0.f; }
    __syncthreads();
    float hw = 0.f;
    for (int j = 3; j > wv; --j) hw = fmaf(wag[j], hw, wag[4 + j]);
    float hin = fmaf(a_ex, hw, b_ex);
    #pragma unroll
    for (int j = 0; j < 13; ++j)
      v[base + j] = fmaf(la[j], hin, lb[j]);
  }
  __syncthreads();
  for (int i = tid; i < Lpx; i += 256){
    float C = pB[(size_t)7*Lpx + i];
    yacc[i + i/56] = fmaf(C, v[i], yacc[i + i/56]);
  }
  __syncthreads();

  if (klo == 0){
    for (int i = tid; i < Lpx; i += 256)
      yo[i] = yacc[i + i/56];
  } else {
    for (int i = tid; i < Lpx; i += 256){
      int q = (i % 56)*56 + i/56;
      yo[i] = yacc[q + q/56];
    }
  }
}

// ---------------- LIF over T=4 + multiply with original x (float4) ----------------
__global__ __launch_bounds__(256) void k_lif2(const float* __restrict__ yo, const float* __restrict__ x0,
                                              float* __restrict__ out){
  const int stride4 = 301056;   // B*C*L/4
  int i4 = blockIdx.x*256 + threadIdx.x;
  float4 v = {0.f,0.f,0.f,0.f};
  #pragma unroll
  for (int t = 0; t < 4; ++t){
    float4 z = *(const float4*)&yo[((size_t)t*stride4 + i4)*4];
    float4 xv = *(const float4*)&x0[((size_t)t*stride4 + i4)*4];
    v.x = 0.5f*(v.x + z.x); v.y = 0.5f*(v.y + z.y);
    v.z = 0.5f*(v.z + z.z); v.w = 0.5f*(v.w + z.w);
    float4 o;
    o.x = (v.x >= 1.0f) ? xv.x : 0.f; o.y = (v.y >= 1.0f) ? xv.y : 0.f;
    o.z = (v.z >= 1.0f) ? xv.z : 0.f; o.w = (v.w >= 1.0f) ? xv.w : 0.f;
    v.x = (v.x >= 1.0f) ? 0.f : v.x; v.y = (v.y >= 1.0f) ? 0.f : v.y;
    v.z = (v.z >= 1.0f) ? 0.f : v.z; v.w = (v.w >= 1.0f) ? 0.f : v.w;
    *(float4*)&out[((size_t)t*stride4 + i4)*4] = o;
  }
}

extern "C" void kernel_launch(void* const* d_in, const int* in_sizes, int n_in,
                              void* d_out, int out_size, void* d_ws, size_t ws_size,
                              hipStream_t stream) {
  const float* x    = (const float*)d_in[0];
  const float* ipw  = (const float*)d_in[1];
  const float* ipb  = (const float*)d_in[2];
  const float* cw   = (const float*)d_in[3];
  const float* cb   = (const float*)d_in[4];
  const float* siw  = (const float*)d_in[5];
  const float* scw  = (const float*)d_in[6];
  const float* xpw  = (const float*)d_in[7];
  const float* dtw  = (const float*)d_in[8];
  const float* dtb  = (const float*)d_in[9];
  const float* alog = (const float*)d_in[10];
  const float* dsv  = (const float*)d_in[11];
  const float* lng  = (const float*)d_in[12];
  const float* lnb  = (const float*)d_in[13];
  const float* opw  = (const float*)d_in[14];

  float* s1 = (float*)d_ws;
  float* s2 = s1 + SZn;
  float* s3 = s2 + SZn;
  float* s4 = s3 + SZn;
  float* pr  = s4 + SZn;
  float* prT = pr + PRJ;

  // 1) in_proj -> xp in s1
  k_matmul<<<784, 256, 0, stream>>>(x, ipw, ipb, s1);
  // 2) LIF over 16 steps -> uchar spikes in s2
  k_lif1<<<294, 256, 0, stream>>>(s1, (unsigned char*)s2);
  // 3) dense 3x3 conv, K-split(3) partials -> s1, s3, s4
  k_conv8<<<dim3(16, 9, 7), 256, 0, stream>>>((const unsigned char*)s2, cw, s1, s3, s4);
  // 4) merge(bias+silu) + ssm_in matmul -> s2
  k_matmulM<<<784, 256, 0, stream>>>(s1, s3, s4, cb, siw, s2);
  // 5) depthwise conv + silu -> xss rm in s1, cm in s3
  k_dwconv<<<1536, 256, 0, stream>>>(s2, scw, s1, s3);
  // 6) projections (pixel-indexed, both layouts)
  k_proj<<<896, 256, 0, stream>>>(s1, xpw, pr, prT);
  // 7) both scan dir-pairs: ya -> s2, yb(row-major) -> s4
  k_scan3<<<dim3(1536, 2), 256, 0, stream>>>(s1, s3, pr, prT, dtw, dtb, alog, dsv, s2, s4);
  // 8) fused LN + out_proj -> s1
  k_matmulLN<<<784, 256, 0, stream>>>(s2, s4, lng, lnb, opw, s1);
  // 9) LIF over T=4, multiply with x -> d_out
  k_lif2<<<1176, 256, 0, stream>>>(s1, x, (float*)d_out);
}